// Round 13
// baseline (400.703 us; speedup 1.0000x reference)
//
#include <hip/hip_runtime.h>
#include <hip/hip_bf16.h>
#include <hip/hip_fp16.h>

// GCN 2-layer encoder: N=100000 nodes, E=3.2M edges, Fin=256, Fh=128, Fo=64.
//   h1 = x@W1 ; a1 = relu(A@h1 + b1) ; h2 = a1@W2 ; out = A@h2 + b2
//
// R13: (a) gemm2 fused INTO agg1: block = 64 nodes (4 waves x 16 nodes,
// same quarter-wave gather), a1 tile written to LDS (bf16), then 4-k-step
// MFMA gemm2 in place -> kills a1's 25.6MB write + 25.6MB read + a launch.
// LDS 22.5KB -> 7 blocks/CU = 28 waves/CU (>= old agg1's 25, latency
// hiding preserved). (b) fp16->f32 unpack via __half22float2 (v_cvt op_sel,
// no shifts/ands) in both agg kernels. Rest = R12: MFMA gemm1 fused with
// LDS-atomic bucketed CSR build; h1/h2 fp16; W^T bf16.

#define FIN 256
#define FH  128
#define FO  64

#define EBLK 8192                     // edges per A-phase block (256 thr x 32)
#define WFX  33554432.0f              // 2^25 fixed-point degree scale
#define WFXI (1.0f / 33554432.0f)

typedef short s16x8 __attribute__((ext_vector_type(8)));
typedef float f32x4 __attribute__((ext_vector_type(4)));

__device__ __forceinline__ float h2f(unsigned int u16) {
  union { unsigned short s; _Float16 h; } c; c.s = (unsigned short)u16;
  return (float)c.h;
}
__device__ __forceinline__ unsigned int f2h(float f) {
  union { _Float16 h; unsigned short s; } c; c.h = (_Float16)f;  // RNE cvt
  return (unsigned int)c.s;
}
__device__ __forceinline__ unsigned int f2bf(float f) {
  union { float f; unsigned int i; } c; c.f = f;
  unsigned int i = c.i;
  return (i + 0x7FFFu + ((i >> 16) & 1u)) >> 16;  // RNE
}
// unpack uint4 of 8 fp16 -> 8 f32 via packed cvt (no shifts)
__device__ __forceinline__ void cvt8(const uint4& v, float* f) {
  const __half2* hp = (const __half2*)&v;
  #pragma unroll
  for (int j = 0; j < 4; ++j) {
    float2 t = __half22float2(hp[j]);
    f[2 * j] = t.x; f[2 * j + 1] = t.y;
  }
}

// ---------------- prep: WT1[j][k]=bf16(W1[k][j]); WT2[j][k]=bf16(W2[k][j])
__global__ __launch_bounds__(256) void prep_w_kernel(
    const float* __restrict__ W1, const float* __restrict__ W2,
    unsigned short* __restrict__ WT1, unsigned short* __restrict__ WT2) {
  int i = blockIdx.x * 256 + threadIdx.x;
  if (i < FIN * FH) {
    int k = i >> 7, j = i & 127;
    WT1[j * FIN + k] = (unsigned short)f2bf(W1[i]);
  } else {
    int i2 = i - FIN * FH;
    if (i2 < FH * FO) {
      int k = i2 >> 6, j = i2 & 63;
      WT2[j * FH + k] = (unsigned short)f2bf(W2[i2]);
    }
  }
}

// ---------------- A1 hist (blocks [0,NBA)) + MFMA gemm1 (blocks [NBA,..))
__global__ __launch_bounds__(256) void a1hist_gemm1_kernel(
    const int* __restrict__ dst, int* __restrict__ gtable, int E,
    int NBA, int NB,
    const float* __restrict__ X, const unsigned short* __restrict__ WT1,
    unsigned short* __restrict__ H1h, int N, int NBG) {
  __shared__ __align__(16) short XS[64 * 40];    // 64 rows x 32 k (bf16)
  __shared__ __align__(16) short WTS[128 * 40];  // 128 cols x 32 k (bf16)
  __shared__ unsigned int bh[392];
  int bid = blockIdx.x;
  int tid = threadIdx.x;
  if (bid < NBA) {
    // ---- bucket-histogram role
    for (int k = tid; k < NB; k += 256) bh[k] = 0u;
    __syncthreads();
    int e0 = bid * EBLK;
    #pragma unroll 4
    for (int it = 0; it < EBLK / 256; ++it) {
      int e = e0 + it * 256 + tid;
      if (e < E) atomicAdd(&bh[dst[e] >> 8], 1u);
    }
    __syncthreads();
    for (int k = tid; k < NB; k += 256)
      gtable[k * NBA + bid] = (int)bh[k];
    return;
  }
  int g = bid - NBA;
  if (g >= NBG) return;
  // ---- MFMA gemm1 role: H1h[64 rows,128 cols] fp16 = X @ W1 (bf16 MFMA)
  int row0 = g * 64;
  int wave = tid >> 6, lane = tid & 63;
  int lr = lane & 15, lq = lane >> 4;          // fragment row & k-octet
  f32x4 acc[8];
  #pragma unroll
  for (int c = 0; c < 8; ++c) acc[c] = (f32x4)(0.f);

  for (int k0 = 0; k0 < FIN; k0 += 32) {
    {  // stage XS: thread t -> row t>>2, koff (t&3)*8 ; f32 -> bf16
      int row = tid >> 2, koff = (tid & 3) * 8;
      int gr = row0 + row;
      float4 va = make_float4(0.f, 0.f, 0.f, 0.f), vb = va;
      if (gr < N) {
        va = *(const float4*)(X + (size_t)gr * FIN + k0 + koff);
        vb = *(const float4*)(X + (size_t)gr * FIN + k0 + koff + 4);
      }
      s16x8 hv;
      hv[0] = (short)f2bf(va.x); hv[1] = (short)f2bf(va.y);
      hv[2] = (short)f2bf(va.z); hv[3] = (short)f2bf(va.w);
      hv[4] = (short)f2bf(vb.x); hv[5] = (short)f2bf(vb.y);
      hv[6] = (short)f2bf(vb.z); hv[7] = (short)f2bf(vb.w);
      *(s16x8*)(&XS[row * 40 + koff]) = hv;
    }
    {  // stage WTS: thread t -> j t>>1, 16-half o (t&1)*16 (WT1 is bf16)
      int j = tid >> 1, o = (tid & 1) * 16;
      uint4 v0 = *(const uint4*)(WT1 + (size_t)j * FIN + k0 + o);
      uint4 v1 = *(const uint4*)(WT1 + (size_t)j * FIN + k0 + o + 8);
      *(uint4*)(&WTS[j * 40 + o]) = v0;
      *(uint4*)(&WTS[j * 40 + o + 8]) = v1;
    }
    __syncthreads();
    s16x8 af = *(const s16x8*)(&XS[(wave * 16 + lr) * 40 + lq * 8]);
    #pragma unroll
    for (int c = 0; c < 8; ++c) {
      s16x8 bf = *(const s16x8*)(&WTS[(c * 16 + lr) * 40 + lq * 8]);
      acc[c] = __builtin_amdgcn_mfma_f32_16x16x32_bf16(af, bf, acc[c], 0, 0, 0);
    }
    __syncthreads();
  }
  // epilogue: D row=(l>>4)*4+r (within wave's 16), col=c*16+(l&15)
  int orow = row0 + wave * 16 + lq * 4;
  #pragma unroll
  for (int c = 0; c < 8; ++c) {
    #pragma unroll
    for (int r = 0; r < 4; ++r) {
      int gr = orow + r;
      if (gr < N)
        H1h[(size_t)gr * FH + c * 16 + lr] = (unsigned short)f2h(acc[c][r]);
    }
  }
}

// ---------------- 3-phase exclusive scan, in-place on int array of length L
__global__ __launch_bounds__(256) void scan1i_kernel(
    int* __restrict__ arr, int* __restrict__ bsum, int L) {
  __shared__ int tot[256];
  int t = threadIdx.x;
  int base = blockIdx.x * 1024 + t * 4;
  int v0 = (base + 0 < L) ? arr[base + 0] : 0;
  int v1 = (base + 1 < L) ? arr[base + 1] : 0;
  int v2 = (base + 2 < L) ? arr[base + 2] : 0;
  int v3 = (base + 3 < L) ? arr[base + 3] : 0;
  int s = v0 + v1 + v2 + v3;
  tot[t] = s;
  __syncthreads();
  for (int off = 1; off < 256; off <<= 1) {
    int y = (t >= off) ? tot[t - off] : 0;
    __syncthreads();
    tot[t] += y;
    __syncthreads();
  }
  int p = tot[t] - s;  // exclusive within block
  if (t == 255) bsum[blockIdx.x] = tot[255];
  if (base + 0 < L) arr[base + 0] = p; p += v0;
  if (base + 1 < L) arr[base + 1] = p; p += v1;
  if (base + 2 < L) arr[base + 2] = p; p += v2;
  if (base + 3 < L) arr[base + 3] = p;
}

__global__ __launch_bounds__(256) void scan2_kernel(
    int* __restrict__ bsum, int nb) {
  __shared__ int buf[256];
  int t = threadIdx.x;
  int v = (t < nb) ? bsum[t] : 0;
  buf[t] = v;
  __syncthreads();
  for (int off = 1; off < 256; off <<= 1) {
    int y = (t >= off) ? buf[t - off] : 0;
    __syncthreads();
    buf[t] += y;
    __syncthreads();
  }
  if (t < nb) bsum[t] = buf[t] - v;  // exclusive
}

__global__ __launch_bounds__(256) void scan3_kernel(
    int* __restrict__ arr, const int* __restrict__ bsum, int L) {
  int i = blockIdx.x * 256 + threadIdx.x;
  if (i < L) arr[i] += bsum[i >> 10];
}

// ---------------- A3: bucketize edges -> bdw[pos] = {w(32) | l(8) | src(20)}
__global__ __launch_bounds__(256) void a3_bucketize_kernel(
    const int* __restrict__ src, const int* __restrict__ dst,
    const float* __restrict__ w, const int* __restrict__ gtable,
    unsigned long long* __restrict__ bdw, int E, int NBA) {
  __shared__ unsigned int bh[392];
  int bid = blockIdx.x;
  int tid = threadIdx.x;
  for (int k = tid; k < 392; k += 256) bh[k] = 0u;
  __syncthreads();
  int e0 = bid * EBLK;
  #pragma unroll 4
  for (int it = 0; it < EBLK / 256; ++it) {
    int e = e0 + it * 256 + tid;
    if (e < E) {
      int d = dst[e];
      int k = d >> 8;
      unsigned int l = (unsigned int)(d & 255);
      unsigned int r = atomicAdd(&bh[k], 1u);
      int pos = gtable[k * NBA + bid] + (int)r;
      unsigned int lo = (unsigned int)src[e] | (l << 20);
      unsigned long long v = ((unsigned long long)__float_as_uint(w[e]) << 32)
                           | (unsigned long long)lo;
      bdw[pos] = v;
    }
  }
}

// ---------------- B1: per-bucket degree + rowptr + dinv (LDS atomics)
__global__ __launch_bounds__(256) void b1_degree_kernel(
    const unsigned long long* __restrict__ bdw,
    const int* __restrict__ gtable, int* __restrict__ rowptr,
    float* __restrict__ dinv, int E, int NBA, int NB, int N) {
  __shared__ unsigned int lcnt[256];
  __shared__ unsigned int lwfx[256];
  __shared__ int sc[256];
  int k = blockIdx.x;
  int t = threadIdx.x;
  lcnt[t] = 0u; lwfx[t] = 0u;
  __syncthreads();
  int base = gtable[k * NBA];
  int end  = (k + 1 < NB) ? gtable[(k + 1) * NBA] : E;
  for (int i = base + t; i < end; i += 256) {
    unsigned long long v = bdw[i];
    unsigned int lo = (unsigned int)v;
    unsigned int l = (lo >> 20) & 0xFFu;
    float wv = __uint_as_float((unsigned int)(v >> 32));
    atomicAdd(&lcnt[l], 1u);
    atomicAdd(&lwfx[l], (unsigned int)(wv * WFX));
  }
  __syncthreads();
  int c = (int)lcnt[t];
  sc[t] = c;
  __syncthreads();
  for (int off = 1; off < 256; off <<= 1) {
    int y = (t >= off) ? sc[t - off] : 0;
    __syncthreads();
    sc[t] += y;
    __syncthreads();
  }
  int excl = sc[t] - c;
  int node = (k << 8) + t;
  if (node < N) {
    rowptr[node] = base + excl;
    float deg = (float)lwfx[t] * WFXI;
    dinv[node] = rsqrtf(1.0f + deg);
  }
  if (k == 0 && t == 0) rowptr[N] = E;
}

// ---------------- B2: per-bucket CSR scatter: edges[rowptr[d]+rank]={src,norm}
__global__ __launch_bounds__(256) void b2_scatter_kernel(
    const unsigned long long* __restrict__ bdw,
    const int* __restrict__ gtable, const int* __restrict__ rowptr,
    const float* __restrict__ dinv, int2* __restrict__ edges,
    int E, int NBA, int NB) {
  __shared__ unsigned int rcnt[256];
  int k = blockIdx.x;
  int t = threadIdx.x;
  rcnt[t] = 0u;
  __syncthreads();
  int base = gtable[k * NBA];
  int end  = (k + 1 < NB) ? gtable[(k + 1) * NBA] : E;
  for (int i = base + t; i < end; i += 256) {
    unsigned long long v = bdw[i];
    unsigned int lo = (unsigned int)v;
    int s = (int)(lo & 0xFFFFFu);
    unsigned int l = (lo >> 20) & 0xFFu;
    float wv = __uint_as_float((unsigned int)(v >> 32));
    unsigned int r = atomicAdd(&rcnt[l], 1u);
    int d = (k << 8) + (int)l;
    int pos = rowptr[d] + (int)r;
    float nm = dinv[s] * wv * dinv[d];
    edges[pos] = make_int2(s, __float_as_int(nm));
  }
}

// ---------------- fused agg1 + gemm2: block = 64 nodes
// phase 1: 4 waves x 16 nodes, quarter-wave gather (16 lanes x 16B), a1->LDS
// phase 2: MFMA gemm2 (a1 tile from LDS), write h2h
__global__ __launch_bounds__(256) void agg1_gemm2_kernel(
    const unsigned short* __restrict__ H1h, const int2* __restrict__ edges,
    const int* __restrict__ rowptr, const float* __restrict__ dinv,
    const float* __restrict__ b1, const unsigned short* __restrict__ WT2,
    unsigned short* __restrict__ H2h, int N) {
  __shared__ __align__(16) short AS[64 * 136];   // a1 tile bf16 (stride 136)
  __shared__ __align__(16) short WTS[64 * 40];   // W2^T k-chunk
  int tid = threadIdx.x;
  int wave = tid >> 6, lane = tid & 63;
  int row0 = blockIdx.x * 64;
  int grp = lane >> 4, li = lane & 15;      // li covers feats li*8..+7
  const size_t rowoff = (size_t)li * 8;

  // ---- phase 1: aggregate 16 nodes per wave
  for (int i = 0; i < 16; ++i) {
    int node = row0 + wave * 16 + i;
    int p0 = 0, p1 = 0;
    if (node < N) { p0 = rowptr[node]; p1 = rowptr[node + 1]; }
    float a0[8], a1v[8];
    #pragma unroll
    for (int j = 0; j < 8; ++j) { a0[j] = 0.f; a1v[j] = 0.f; }
    int p = p0;
    for (; p + 8 <= p1; p += 8) {
      int2 e0 = edges[p + grp];
      int2 e1 = edges[p + 4 + grp];
      uint4 h0 = *(const uint4*)(H1h + (size_t)e0.x * FH + rowoff);
      uint4 h1 = *(const uint4*)(H1h + (size_t)e1.x * FH + rowoff);
      float n0 = __int_as_float(e0.y), n1 = __int_as_float(e1.y);
      float f0[8], f1[8];
      cvt8(h0, f0); cvt8(h1, f1);
      #pragma unroll
      for (int j = 0; j < 8; ++j) {
        a0[j] += n0 * f0[j];
        a1v[j] += n1 * f1[j];
      }
    }
    for (; p + 4 <= p1; p += 4) {
      int2 e0 = edges[p + grp];
      uint4 h0 = *(const uint4*)(H1h + (size_t)e0.x * FH + rowoff);
      float n0 = __int_as_float(e0.y);
      float f0[8];
      cvt8(h0, f0);
      #pragma unroll
      for (int j = 0; j < 8; ++j) a0[j] += n0 * f0[j];
    }
    if (p < p1) {  // 1..3 leftover edges: masked
      int q = p + grp;
      int qi = (q < p1) ? q : p;
      int2 e0 = edges[qi];
      float n0 = (q < p1) ? __int_as_float(e0.y) : 0.f;
      uint4 h0 = *(const uint4*)(H1h + (size_t)e0.x * FH + rowoff);
      float f0[8];
      cvt8(h0, f0);
      #pragma unroll
      for (int j = 0; j < 8; ++j) a0[j] += n0 * f0[j];
    }
    float s[8];
    #pragma unroll
    for (int j = 0; j < 8; ++j) {
      s[j] = a0[j] + a1v[j];
      s[j] += __shfl_xor(s[j], 16);
      s[j] += __shfl_xor(s[j], 32);
    }
    if (lane < 16) {
      uint4 pk = make_uint4(0u, 0u, 0u, 0u);
      if (node < N) {
        float di = dinv[node], sn = di * di;
        uint4 hs = *(const uint4*)(H1h + (size_t)node * FH + rowoff);
        float fs[8];
        cvt8(hs, fs);
        #pragma unroll
        for (int j = 0; j < 8; ++j) s[j] += sn * fs[j];
        float4 bv0 = *(const float4*)(b1 + li * 8);
        float4 bv1 = *(const float4*)(b1 + li * 8 + 4);
        s[0] = fmaxf(s[0] + bv0.x, 0.f); s[1] = fmaxf(s[1] + bv0.y, 0.f);
        s[2] = fmaxf(s[2] + bv0.z, 0.f); s[3] = fmaxf(s[3] + bv0.w, 0.f);
        s[4] = fmaxf(s[4] + bv1.x, 0.f); s[5] = fmaxf(s[5] + bv1.y, 0.f);
        s[6] = fmaxf(s[6] + bv1.z, 0.f); s[7] = fmaxf(s[7] + bv1.w, 0.f);
        pk.x = f2bf(s[0]) | (f2bf(s[1]) << 16);
        pk.y = f2bf(s[2]) | (f2bf(s[3]) << 16);
        pk.z = f2bf(s[4]) | (f2bf(s[5]) << 16);
        pk.w = f2bf(s[6]) | (f2bf(s[7]) << 16);
      }
      *(uint4*)(&AS[(wave * 16 + i) * 136 + li * 8]) = pk;
    }
  }
  __syncthreads();

  // ---- phase 2: MFMA gemm2, A = AS (LDS), B = WT2
  f32x4 acc[4];
  #pragma unroll
  for (int c = 0; c < 4; ++c) acc[c] = (f32x4)(0.f);
  for (int k0 = 0; k0 < FH; k0 += 32) {
    {  // stage WTS: j=t>>2, o=(t&3)*8
      int j = tid >> 2, o = (tid & 3) * 8;
      uint4 v = *(const uint4*)(WT2 + (size_t)j * FH + k0 + o);
      *(uint4*)(&WTS[j * 40 + o]) = v;
    }
    __syncthreads();
    s16x8 af = *(const s16x8*)(&AS[(wave * 16 + li) * 136 + k0 + grp * 8]);
    #pragma unroll
    for (int c = 0; c < 4; ++c) {
      s16x8 bf = *(const s16x8*)(&WTS[(c * 16 + li) * 40 + grp * 8]);
      acc[c] = __builtin_amdgcn_mfma_f32_16x16x32_bf16(af, bf, acc[c], 0, 0, 0);
    }
    __syncthreads();
  }
  int orow = row0 + wave * 16 + grp * 4;
  #pragma unroll
  for (int c = 0; c < 4; ++c) {
    #pragma unroll
    for (int r = 0; r < 4; ++r) {
      int gr = orow + r;
      if (gr < N)
        H2h[(size_t)gr * FO + c * 16 + li] = (unsigned short)f2h(acc[c][r]);
    }
  }
}

// ---------------- agg2: out = A @ h2 + b2, 64 fp16 feats
// eighth-wave per row: 8 lanes x 16B; 8 edges/wave x2 unroll = 16 in flight
__global__ __launch_bounds__(256) void agg2_kernel(
    const unsigned short* __restrict__ H2h, const int2* __restrict__ edges,
    const int* __restrict__ rowptr, const float* __restrict__ dinv,
    const float* __restrict__ b2, float* __restrict__ OUT, int N) {
  int wid = (blockIdx.x * 256 + threadIdx.x) >> 6;
  int lane = threadIdx.x & 63;
  if (wid >= N) return;
  int p0 = rowptr[wid], p1 = rowptr[wid + 1];
  int grp = lane >> 3, li = lane & 7;       // li covers feats li*8..+7
  const size_t rowoff = (size_t)li * 8;
  float a0[8], a1v[8];
  #pragma unroll
  for (int j = 0; j < 8; ++j) { a0[j] = 0.f; a1v[j] = 0.f; }

  int p = p0;
  for (; p + 16 <= p1; p += 16) {
    int2 e0 = edges[p + grp];
    int2 e1 = edges[p + 8 + grp];
    uint4 h0 = *(const uint4*)(H2h + (size_t)e0.x * FO + rowoff);
    uint4 h1 = *(const uint4*)(H2h + (size_t)e1.x * FO + rowoff);
    float n0 = __int_as_float(e0.y), n1 = __int_as_float(e1.y);
    float f0[8], f1[8];
    cvt8(h0, f0); cvt8(h1, f1);
    #pragma unroll
    for (int j = 0; j < 8; ++j) {
      a0[j] += n0 * f0[j];
      a1v[j] += n1 * f1[j];
    }
  }
  for (; p + 8 <= p1; p += 8) {
    int2 e0 = edges[p + grp];
    uint4 h0 = *(const uint4*)(H2h + (size_t)e0.x * FO + rowoff);
    float n0 = __int_as_float(e0.y);
    float f0[8];
    cvt8(h0, f0);
    #pragma unroll
    for (int j = 0; j < 8; ++j) a0[j] += n0 * f0[j];
  }
  if (p < p1) {  // 1..7 leftover edges: masked
    int q = p + grp;
    int qi = (q < p1) ? q : p;
    int2 e0 = edges[qi];
    float n0 = (q < p1) ? __int_as_float(e0.y) : 0.f;
    uint4 h0 = *(const uint4*)(H2h + (size_t)e0.x * FO + rowoff);
    float f0[8];
    cvt8(h0, f0);
    #pragma unroll
    for (int j = 0; j < 8; ++j) a0[j] += n0 * f0[j];
  }
  float s[8];
  #pragma unroll
  for (int j = 0; j < 8; ++j) {
    s[j] = a0[j] + a1v[j];
    s[j] += __shfl_xor(s[j], 8);
    s[j] += __shfl_xor(s[j], 16);
    s[j] += __shfl_xor(s[j], 32);
  }
  if (lane < 8) {
    float di = dinv[wid], sn = di * di;
    uint4 hs = *(const uint4*)(H2h + (size_t)wid * FO + rowoff);
    float fs[8];
    cvt8(hs, fs);
    #pragma unroll
    for (int j = 0; j < 8; ++j) s[j] += sn * fs[j];
    float4 bv0 = *(const float4*)(b2 + li * 8);
    float4 bv1 = *(const float4*)(b2 + li * 8 + 4);
    float4 o0 = make_float4(s[0] + bv0.x, s[1] + bv0.y, s[2] + bv0.z, s[3] + bv0.w);
    float4 o1 = make_float4(s[4] + bv1.x, s[5] + bv1.y, s[6] + bv1.z, s[7] + bv1.w);
    *(float4*)(OUT + (size_t)wid * FO + li * 8) = o0;
    *(float4*)(OUT + (size_t)wid * FO + li * 8 + 4) = o1;
  }
}

extern "C" void kernel_launch(void* const* d_in, const int* in_sizes, int n_in,
                              void* d_out, int out_size, void* d_ws, size_t ws_size,
                              hipStream_t stream) {
  const float* x  = (const float*)d_in[0];
  const int*   ei = (const int*)d_in[1];
  const float* ew = (const float*)d_in[2];
  const float* W1 = (const float*)d_in[3];
  const float* b1 = (const float*)d_in[4];
  const float* W2 = (const float*)d_in[5];
  const float* b2 = (const float*)d_in[6];
  float* out = (float*)d_out;

  const int N = in_sizes[0] / FIN;        // 100000
  const int E = in_sizes[2];              // 3200000
  const int* src = ei;
  const int* dst = ei + E;
  const int NBG = (N + 63) / 64;          // gemm1 tiles (1563)
  const int NBA = (E + EBLK - 1) / EBLK;  // A-phase blocks (391)
  const int NB  = (N + 255) / 256;        // buckets (391)
  const int L   = NB * NBA;               // gtable length (152,881)
  const int nsb = (L + 1023) / 1024;      // scan blocks (150, <=256)

  // workspace layout (16B-aligned slices), ~92MB total
  char* ws = (char*)d_ws;
  size_t off = 0;
  unsigned short* h1h = (unsigned short*)(ws + off); off += (size_t)N * FH * 2;  // fp16 h1
  unsigned short* h2h = (unsigned short*)(ws + off); off += (size_t)N * FO * 2;  // fp16 h2
  int2*  edges  = (int2*) (ws + off); off += (size_t)E * 8;
  unsigned long long* bdw = (unsigned long long*)(ws + off); off += (size_t)E * 8;
  int*   gtable = (int*)  (ws + off); off += (((size_t)L * 4) + 15) & ~(size_t)15;
  int*   rowptr = (int*)  (ws + off); off += (((size_t)(N + 1) * 4) + 15) & ~(size_t)15;
  float* dinv   = (float*)(ws + off); off += (size_t)N * 4;
  int*   bsum   = (int*)  (ws + off); off += 1024;
  unsigned short* WT1 = (unsigned short*)(ws + off); off += (size_t)FH * FIN * 2;  // bf16 W1^T
  unsigned short* WT2 = (unsigned short*)(ws + off); off += (size_t)FO * FH * 2;   // bf16 W2^T

  // weight transpose + bf16 cvt (tiny, off critical path)
  prep_w_kernel<<<(FIN * FH + FH * FO + 255) / 256, 256, 0, stream>>>(W1, W2, WT1, WT2);
  // CSR build (LDS-atomic bucketed) + MFMA gemm1 fused
  a1hist_gemm1_kernel<<<NBA + NBG, 256, 0, stream>>>(dst, gtable, E, NBA, NB,
                                                     x, WT1, h1h, N, NBG);
  scan1i_kernel<<<nsb, 256, 0, stream>>>(gtable, bsum, L);
  scan2_kernel<<<1, 256, 0, stream>>>(bsum, nsb);
  scan3_kernel<<<(L + 255) / 256, 256, 0, stream>>>(gtable, bsum, L);
  a3_bucketize_kernel<<<NBA, 256, 0, stream>>>(src, dst, ew, gtable, bdw, E, NBA);
  b1_degree_kernel<<<NB, 256, 0, stream>>>(bdw, gtable, rowptr, dinv, E, NBA, NB, N);
  b2_scatter_kernel<<<NB, 256, 0, stream>>>(bdw, gtable, rowptr, dinv, edges,
                                            E, NBA, NB);
  // layers: agg1+gemm2 fused, then agg2
  agg1_gemm2_kernel<<<NBG, 256, 0, stream>>>(h1h, edges, rowptr, dinv, b1,
                                             WT2, h2h, N);
  agg2_kernel<<<(N * 64 + 255) / 256, 256, 0, stream>>>(h2h, edges, rowptr,
                                                        dinv, b2, out, N);
}

// Round 14
// 370.239 us; speedup vs baseline: 1.0823x; 1.0823x over previous
//
#include <hip/hip_runtime.h>
#include <hip/hip_bf16.h>
#include <hip/hip_fp16.h>

// GCN 2-layer encoder: N=100000 nodes, E=3.2M edges, Fin=256, Fh=128, Fo=64.
//   h1 = x@W1 ; a1 = relu(A@h1 + b1) ; h2 = a1@W2 ; out = A@h2 + b2
//
// R14 = R12 structure (separate agg1 / gemm2 — R13's fusion cost 48us of
// latency-hiding for 8us of traffic: occupancy 77->42%) + R13's cvt8
// packed fp16->f32 unpack (no shifts) + agg1 unroll x3 (12 rows in
// flight/wave; VGPR ~32, occupancy preserved). MFMA gemm1 fused with
// LDS-atomic bucketed CSR build; MFMA gemm2; h1/h2 fp16, a1 bf16, W^T bf16.

#define FIN 256
#define FH  128
#define FO  64

#define EBLK 8192                     // edges per A-phase block (256 thr x 32)
#define WFX  33554432.0f              // 2^25 fixed-point degree scale
#define WFXI (1.0f / 33554432.0f)

typedef short s16x8 __attribute__((ext_vector_type(8)));
typedef float f32x4 __attribute__((ext_vector_type(4)));

__device__ __forceinline__ unsigned int f2h(float f) {
  union { _Float16 h; unsigned short s; } c; c.h = (_Float16)f;  // RNE cvt
  return (unsigned int)c.s;
}
__device__ __forceinline__ unsigned int f2bf(float f) {
  union { float f; unsigned int i; } c; c.f = f;
  unsigned int i = c.i;
  return (i + 0x7FFFu + ((i >> 16) & 1u)) >> 16;  // RNE
}
// unpack uint4 of 8 fp16 -> 8 f32 via packed cvt (no shifts)
__device__ __forceinline__ void cvt8(const uint4& v, float* f) {
  const __half2* hp = (const __half2*)&v;
  #pragma unroll
  for (int j = 0; j < 4; ++j) {
    float2 t = __half22float2(hp[j]);
    f[2 * j] = t.x; f[2 * j + 1] = t.y;
  }
}

// ---------------- prep: WT1[j][k]=bf16(W1[k][j]); WT2[j][k]=bf16(W2[k][j])
__global__ __launch_bounds__(256) void prep_w_kernel(
    const float* __restrict__ W1, const float* __restrict__ W2,
    unsigned short* __restrict__ WT1, unsigned short* __restrict__ WT2) {
  int i = blockIdx.x * 256 + threadIdx.x;
  if (i < FIN * FH) {
    int k = i >> 7, j = i & 127;
    WT1[j * FIN + k] = (unsigned short)f2bf(W1[i]);
  } else {
    int i2 = i - FIN * FH;
    if (i2 < FH * FO) {
      int k = i2 >> 6, j = i2 & 63;
      WT2[j * FH + k] = (unsigned short)f2bf(W2[i2]);
    }
  }
}

// ---------------- A1 hist (blocks [0,NBA)) + MFMA gemm1 (blocks [NBA,..))
__global__ __launch_bounds__(256) void a1hist_gemm1_kernel(
    const int* __restrict__ dst, int* __restrict__ gtable, int E,
    int NBA, int NB,
    const float* __restrict__ X, const unsigned short* __restrict__ WT1,
    unsigned short* __restrict__ H1h, int N, int NBG) {
  __shared__ __align__(16) short XS[64 * 40];    // 64 rows x 32 k (bf16)
  __shared__ __align__(16) short WTS[128 * 40];  // 128 cols x 32 k (bf16)
  __shared__ unsigned int bh[392];
  int bid = blockIdx.x;
  int tid = threadIdx.x;
  if (bid < NBA) {
    // ---- bucket-histogram role
    for (int k = tid; k < NB; k += 256) bh[k] = 0u;
    __syncthreads();
    int e0 = bid * EBLK;
    #pragma unroll 4
    for (int it = 0; it < EBLK / 256; ++it) {
      int e = e0 + it * 256 + tid;
      if (e < E) atomicAdd(&bh[dst[e] >> 8], 1u);
    }
    __syncthreads();
    for (int k = tid; k < NB; k += 256)
      gtable[k * NBA + bid] = (int)bh[k];
    return;
  }
  int g = bid - NBA;
  if (g >= NBG) return;
  // ---- MFMA gemm1 role: H1h[64 rows,128 cols] fp16 = X @ W1 (bf16 MFMA)
  int row0 = g * 64;
  int wave = tid >> 6, lane = tid & 63;
  int lr = lane & 15, lq = lane >> 4;          // fragment row & k-octet
  f32x4 acc[8];
  #pragma unroll
  for (int c = 0; c < 8; ++c) acc[c] = (f32x4)(0.f);

  for (int k0 = 0; k0 < FIN; k0 += 32) {
    {  // stage XS: thread t -> row t>>2, koff (t&3)*8 ; f32 -> bf16
      int row = tid >> 2, koff = (tid & 3) * 8;
      int gr = row0 + row;
      float4 va = make_float4(0.f, 0.f, 0.f, 0.f), vb = va;
      if (gr < N) {
        va = *(const float4*)(X + (size_t)gr * FIN + k0 + koff);
        vb = *(const float4*)(X + (size_t)gr * FIN + k0 + koff + 4);
      }
      s16x8 hv;
      hv[0] = (short)f2bf(va.x); hv[1] = (short)f2bf(va.y);
      hv[2] = (short)f2bf(va.z); hv[3] = (short)f2bf(va.w);
      hv[4] = (short)f2bf(vb.x); hv[5] = (short)f2bf(vb.y);
      hv[6] = (short)f2bf(vb.z); hv[7] = (short)f2bf(vb.w);
      *(s16x8*)(&XS[row * 40 + koff]) = hv;
    }
    {  // stage WTS: thread t -> j t>>1, 16-half o (t&1)*16 (WT1 is bf16)
      int j = tid >> 1, o = (tid & 1) * 16;
      uint4 v0 = *(const uint4*)(WT1 + (size_t)j * FIN + k0 + o);
      uint4 v1 = *(const uint4*)(WT1 + (size_t)j * FIN + k0 + o + 8);
      *(uint4*)(&WTS[j * 40 + o]) = v0;
      *(uint4*)(&WTS[j * 40 + o + 8]) = v1;
    }
    __syncthreads();
    s16x8 af = *(const s16x8*)(&XS[(wave * 16 + lr) * 40 + lq * 8]);
    #pragma unroll
    for (int c = 0; c < 8; ++c) {
      s16x8 bf = *(const s16x8*)(&WTS[(c * 16 + lr) * 40 + lq * 8]);
      acc[c] = __builtin_amdgcn_mfma_f32_16x16x32_bf16(af, bf, acc[c], 0, 0, 0);
    }
    __syncthreads();
  }
  // epilogue: D row=(l>>4)*4+r (within wave's 16), col=c*16+(l&15)
  int orow = row0 + wave * 16 + lq * 4;
  #pragma unroll
  for (int c = 0; c < 8; ++c) {
    #pragma unroll
    for (int r = 0; r < 4; ++r) {
      int gr = orow + r;
      if (gr < N)
        H1h[(size_t)gr * FH + c * 16 + lr] = (unsigned short)f2h(acc[c][r]);
    }
  }
}

// ---------------- 3-phase exclusive scan, in-place on int array of length L
__global__ __launch_bounds__(256) void scan1i_kernel(
    int* __restrict__ arr, int* __restrict__ bsum, int L) {
  __shared__ int tot[256];
  int t = threadIdx.x;
  int base = blockIdx.x * 1024 + t * 4;
  int v0 = (base + 0 < L) ? arr[base + 0] : 0;
  int v1 = (base + 1 < L) ? arr[base + 1] : 0;
  int v2 = (base + 2 < L) ? arr[base + 2] : 0;
  int v3 = (base + 3 < L) ? arr[base + 3] : 0;
  int s = v0 + v1 + v2 + v3;
  tot[t] = s;
  __syncthreads();
  for (int off = 1; off < 256; off <<= 1) {
    int y = (t >= off) ? tot[t - off] : 0;
    __syncthreads();
    tot[t] += y;
    __syncthreads();
  }
  int p = tot[t] - s;  // exclusive within block
  if (t == 255) bsum[blockIdx.x] = tot[255];
  if (base + 0 < L) arr[base + 0] = p; p += v0;
  if (base + 1 < L) arr[base + 1] = p; p += v1;
  if (base + 2 < L) arr[base + 2] = p; p += v2;
  if (base + 3 < L) arr[base + 3] = p;
}

__global__ __launch_bounds__(256) void scan2_kernel(
    int* __restrict__ bsum, int nb) {
  __shared__ int buf[256];
  int t = threadIdx.x;
  int v = (t < nb) ? bsum[t] : 0;
  buf[t] = v;
  __syncthreads();
  for (int off = 1; off < 256; off <<= 1) {
    int y = (t >= off) ? buf[t - off] : 0;
    __syncthreads();
    buf[t] += y;
    __syncthreads();
  }
  if (t < nb) bsum[t] = buf[t] - v;  // exclusive
}

__global__ __launch_bounds__(256) void scan3_kernel(
    int* __restrict__ arr, const int* __restrict__ bsum, int L) {
  int i = blockIdx.x * 256 + threadIdx.x;
  if (i < L) arr[i] += bsum[i >> 10];
}

// ---------------- A3: bucketize edges -> bdw[pos] = {w(32) | l(8) | src(20)}
__global__ __launch_bounds__(256) void a3_bucketize_kernel(
    const int* __restrict__ src, const int* __restrict__ dst,
    const float* __restrict__ w, const int* __restrict__ gtable,
    unsigned long long* __restrict__ bdw, int E, int NBA) {
  __shared__ unsigned int bh[392];
  int bid = blockIdx.x;
  int tid = threadIdx.x;
  for (int k = tid; k < 392; k += 256) bh[k] = 0u;
  __syncthreads();
  int e0 = bid * EBLK;
  #pragma unroll 4
  for (int it = 0; it < EBLK / 256; ++it) {
    int e = e0 + it * 256 + tid;
    if (e < E) {
      int d = dst[e];
      int k = d >> 8;
      unsigned int l = (unsigned int)(d & 255);
      unsigned int r = atomicAdd(&bh[k], 1u);
      int pos = gtable[k * NBA + bid] + (int)r;
      unsigned int lo = (unsigned int)src[e] | (l << 20);
      unsigned long long v = ((unsigned long long)__float_as_uint(w[e]) << 32)
                           | (unsigned long long)lo;
      bdw[pos] = v;
    }
  }
}

// ---------------- B1: per-bucket degree + rowptr + dinv (LDS atomics)
__global__ __launch_bounds__(256) void b1_degree_kernel(
    const unsigned long long* __restrict__ bdw,
    const int* __restrict__ gtable, int* __restrict__ rowptr,
    float* __restrict__ dinv, int E, int NBA, int NB, int N) {
  __shared__ unsigned int lcnt[256];
  __shared__ unsigned int lwfx[256];
  __shared__ int sc[256];
  int k = blockIdx.x;
  int t = threadIdx.x;
  lcnt[t] = 0u; lwfx[t] = 0u;
  __syncthreads();
  int base = gtable[k * NBA];
  int end  = (k + 1 < NB) ? gtable[(k + 1) * NBA] : E;
  for (int i = base + t; i < end; i += 256) {
    unsigned long long v = bdw[i];
    unsigned int lo = (unsigned int)v;
    unsigned int l = (lo >> 20) & 0xFFu;
    float wv = __uint_as_float((unsigned int)(v >> 32));
    atomicAdd(&lcnt[l], 1u);
    atomicAdd(&lwfx[l], (unsigned int)(wv * WFX));
  }
  __syncthreads();
  int c = (int)lcnt[t];
  sc[t] = c;
  __syncthreads();
  for (int off = 1; off < 256; off <<= 1) {
    int y = (t >= off) ? sc[t - off] : 0;
    __syncthreads();
    sc[t] += y;
    __syncthreads();
  }
  int excl = sc[t] - c;
  int node = (k << 8) + t;
  if (node < N) {
    rowptr[node] = base + excl;
    float deg = (float)lwfx[t] * WFXI;
    dinv[node] = rsqrtf(1.0f + deg);
  }
  if (k == 0 && t == 0) rowptr[N] = E;
}

// ---------------- B2: per-bucket CSR scatter: edges[rowptr[d]+rank]={src,norm}
__global__ __launch_bounds__(256) void b2_scatter_kernel(
    const unsigned long long* __restrict__ bdw,
    const int* __restrict__ gtable, const int* __restrict__ rowptr,
    const float* __restrict__ dinv, int2* __restrict__ edges,
    int E, int NBA, int NB) {
  __shared__ unsigned int rcnt[256];
  int k = blockIdx.x;
  int t = threadIdx.x;
  rcnt[t] = 0u;
  __syncthreads();
  int base = gtable[k * NBA];
  int end  = (k + 1 < NB) ? gtable[(k + 1) * NBA] : E;
  for (int i = base + t; i < end; i += 256) {
    unsigned long long v = bdw[i];
    unsigned int lo = (unsigned int)v;
    int s = (int)(lo & 0xFFFFFu);
    unsigned int l = (lo >> 20) & 0xFFu;
    float wv = __uint_as_float((unsigned int)(v >> 32));
    unsigned int r = atomicAdd(&rcnt[l], 1u);
    int d = (k << 8) + (int)l;
    int pos = rowptr[d] + (int)r;
    float nm = dinv[s] * wv * dinv[d];
    edges[pos] = make_int2(s, __float_as_int(nm));
  }
}

// ---------------- MFMA GEMM2: H2h[N,64] fp16 = A1b[N,128] bf16 @ W2
__global__ __launch_bounds__(256) void gemm2_kernel(
    const unsigned short* __restrict__ A1b, const unsigned short* __restrict__ WT2,
    unsigned short* __restrict__ H2h, int N) {
  __shared__ __align__(16) short XS[64 * 40];   // 64 rows x 32 k
  __shared__ __align__(16) short WTS[64 * 40];  // 64 cols x 32 k
  int tid = threadIdx.x;
  int row0 = blockIdx.x * 64;
  int wave = tid >> 6, lane = tid & 63;
  int lr = lane & 15, lq = lane >> 4;
  f32x4 acc[4];
  #pragma unroll
  for (int c = 0; c < 4; ++c) acc[c] = (f32x4)(0.f);

  for (int k0 = 0; k0 < FH; k0 += 32) {
    {  // stage XS: row=t>>2, o=(t&3)*8 (A1b already bf16)
      int row = tid >> 2, o = (tid & 3) * 8;
      int gr = row0 + row;
      uint4 v = make_uint4(0u, 0u, 0u, 0u);
      if (gr < N) v = *(const uint4*)(A1b + (size_t)gr * FH + k0 + o);
      *(uint4*)(&XS[row * 40 + o]) = v;
    }
    {  // stage WTS: j=t>>2, o=(t&3)*8
      int j = tid >> 2, o = (tid & 3) * 8;
      uint4 v = *(const uint4*)(WT2 + (size_t)j * FH + k0 + o);
      *(uint4*)(&WTS[j * 40 + o]) = v;
    }
    __syncthreads();
    s16x8 af = *(const s16x8*)(&XS[(wave * 16 + lr) * 40 + lq * 8]);
    #pragma unroll
    for (int c = 0; c < 4; ++c) {
      s16x8 bf = *(const s16x8*)(&WTS[(c * 16 + lr) * 40 + lq * 8]);
      acc[c] = __builtin_amdgcn_mfma_f32_16x16x32_bf16(af, bf, acc[c], 0, 0, 0);
    }
    __syncthreads();
  }
  int orow = row0 + wave * 16 + lq * 4;
  #pragma unroll
  for (int c = 0; c < 4; ++c) {
    #pragma unroll
    for (int r = 0; r < 4; ++r) {
      int gr = orow + r;
      if (gr < N)
        H2h[(size_t)gr * FO + c * 16 + lr] = (unsigned short)f2h(acc[c][r]);
    }
  }
}

// ---------------- agg1: a1b = relu(A @ h1 + b1), out bf16 (feeds MFMA gemm2)
// quarter-wave per row: 16 lanes x 16B; 4 edges/wave x3 unroll = 12 in flight
__global__ __launch_bounds__(256) void agg1_kernel(
    const unsigned short* __restrict__ H1h, const int2* __restrict__ edges,
    const int* __restrict__ rowptr, const float* __restrict__ dinv,
    const float* __restrict__ b1, unsigned short* __restrict__ A1b, int N) {
  int wid = (blockIdx.x * 256 + threadIdx.x) >> 6;
  int lane = threadIdx.x & 63;
  if (wid >= N) return;
  int p0 = rowptr[wid], p1 = rowptr[wid + 1];
  int grp = lane >> 4, li = lane & 15;      // li covers feats li*8..+7
  const size_t rowoff = (size_t)li * 8;
  float a0[8], a1v[8], a2v[8];
  #pragma unroll
  for (int j = 0; j < 8; ++j) { a0[j] = 0.f; a1v[j] = 0.f; a2v[j] = 0.f; }

  int p = p0;
  for (; p + 12 <= p1; p += 12) {
    int2 e0 = edges[p + grp];
    int2 e1 = edges[p + 4 + grp];
    int2 e2 = edges[p + 8 + grp];
    uint4 h0 = *(const uint4*)(H1h + (size_t)e0.x * FH + rowoff);
    uint4 h1 = *(const uint4*)(H1h + (size_t)e1.x * FH + rowoff);
    uint4 h2 = *(const uint4*)(H1h + (size_t)e2.x * FH + rowoff);
    float n0 = __int_as_float(e0.y), n1 = __int_as_float(e1.y);
    float n2 = __int_as_float(e2.y);
    float f0[8], f1[8], f2[8];
    cvt8(h0, f0); cvt8(h1, f1); cvt8(h2, f2);
    #pragma unroll
    for (int j = 0; j < 8; ++j) {
      a0[j] += n0 * f0[j];
      a1v[j] += n1 * f1[j];
      a2v[j] += n2 * f2[j];
    }
  }
  for (; p + 4 <= p1; p += 4) {
    int2 e0 = edges[p + grp];
    uint4 h0 = *(const uint4*)(H1h + (size_t)e0.x * FH + rowoff);
    float n0 = __int_as_float(e0.y);
    float f0[8];
    cvt8(h0, f0);
    #pragma unroll
    for (int j = 0; j < 8; ++j) a0[j] += n0 * f0[j];
  }
  if (p < p1) {  // 1..3 leftover edges: masked
    int q = p + grp;
    int qi = (q < p1) ? q : p;
    int2 e0 = edges[qi];
    float n0 = (q < p1) ? __int_as_float(e0.y) : 0.f;
    uint4 h0 = *(const uint4*)(H1h + (size_t)e0.x * FH + rowoff);
    float f0[8];
    cvt8(h0, f0);
    #pragma unroll
    for (int j = 0; j < 8; ++j) a0[j] += n0 * f0[j];
  }
  float s[8];
  #pragma unroll
  for (int j = 0; j < 8; ++j) {
    s[j] = (a0[j] + a1v[j]) + a2v[j];
    s[j] += __shfl_xor(s[j], 16);
    s[j] += __shfl_xor(s[j], 32);
  }
  if (lane < 16) {
    float di = dinv[wid], sn = di * di;
    uint4 hs = *(const uint4*)(H1h + (size_t)wid * FH + rowoff);
    float fs[8];
    cvt8(hs, fs);
    #pragma unroll
    for (int j = 0; j < 8; ++j) s[j] += sn * fs[j];
    float4 bv0 = *(const float4*)(b1 + li * 8);
    float4 bv1 = *(const float4*)(b1 + li * 8 + 4);
    s[0] = fmaxf(s[0] + bv0.x, 0.f); s[1] = fmaxf(s[1] + bv0.y, 0.f);
    s[2] = fmaxf(s[2] + bv0.z, 0.f); s[3] = fmaxf(s[3] + bv0.w, 0.f);
    s[4] = fmaxf(s[4] + bv1.x, 0.f); s[5] = fmaxf(s[5] + bv1.y, 0.f);
    s[6] = fmaxf(s[6] + bv1.z, 0.f); s[7] = fmaxf(s[7] + bv1.w, 0.f);
    uint4 pk;
    pk.x = f2bf(s[0]) | (f2bf(s[1]) << 16);
    pk.y = f2bf(s[2]) | (f2bf(s[3]) << 16);
    pk.z = f2bf(s[4]) | (f2bf(s[5]) << 16);
    pk.w = f2bf(s[6]) | (f2bf(s[7]) << 16);
    *(uint4*)(A1b + (size_t)wid * FH + li * 8) = pk;
  }
}

// ---------------- agg2: out = A @ h2 + b2, 64 fp16 feats
// eighth-wave per row: 8 lanes x 16B; 8 edges/wave x2 unroll = 16 in flight
__global__ __launch_bounds__(256) void agg2_kernel(
    const unsigned short* __restrict__ H2h, const int2* __restrict__ edges,
    const int* __restrict__ rowptr, const float* __restrict__ dinv,
    const float* __restrict__ b2, float* __restrict__ OUT, int N) {
  int wid = (blockIdx.x * 256 + threadIdx.x) >> 6;
  int lane = threadIdx.x & 63;
  if (wid >= N) return;
  int p0 = rowptr[wid], p1 = rowptr[wid + 1];
  int grp = lane >> 3, li = lane & 7;       // li covers feats li*8..+7
  const size_t rowoff = (size_t)li * 8;
  float a0[8], a1v[8];
  #pragma unroll
  for (int j = 0; j < 8; ++j) { a0[j] = 0.f; a1v[j] = 0.f; }

  int p = p0;
  for (; p + 16 <= p1; p += 16) {
    int2 e0 = edges[p + grp];
    int2 e1 = edges[p + 8 + grp];
    uint4 h0 = *(const uint4*)(H2h + (size_t)e0.x * FO + rowoff);
    uint4 h1 = *(const uint4*)(H2h + (size_t)e1.x * FO + rowoff);
    float n0 = __int_as_float(e0.y), n1 = __int_as_float(e1.y);
    float f0[8], f1[8];
    cvt8(h0, f0); cvt8(h1, f1);
    #pragma unroll
    for (int j = 0; j < 8; ++j) {
      a0[j] += n0 * f0[j];
      a1v[j] += n1 * f1[j];
    }
  }
  for (; p + 8 <= p1; p += 8) {
    int2 e0 = edges[p + grp];
    uint4 h0 = *(const uint4*)(H2h + (size_t)e0.x * FO + rowoff);
    float n0 = __int_as_float(e0.y);
    float f0[8];
    cvt8(h0, f0);
    #pragma unroll
    for (int j = 0; j < 8; ++j) a0[j] += n0 * f0[j];
  }
  if (p < p1) {  // 1..7 leftover edges: masked
    int q = p + grp;
    int qi = (q < p1) ? q : p;
    int2 e0 = edges[qi];
    float n0 = (q < p1) ? __int_as_float(e0.y) : 0.f;
    uint4 h0 = *(const uint4*)(H2h + (size_t)e0.x * FO + rowoff);
    float f0[8];
    cvt8(h0, f0);
    #pragma unroll
    for (int j = 0; j < 8; ++j) a0[j] += n0 * f0[j];
  }
  float s[8];
  #pragma unroll
  for (int j = 0; j < 8; ++j) {
    s[j] = a0[j] + a1v[j];
    s[j] += __shfl_xor(s[j], 8);
    s[j] += __shfl_xor(s[j], 16);
    s[j] += __shfl_xor(s[j], 32);
  }
  if (lane < 8) {
    float di = dinv[wid], sn = di * di;
    uint4 hs = *(const uint4*)(H2h + (size_t)wid * FO + rowoff);
    float fs[8];
    cvt8(hs, fs);
    #pragma unroll
    for (int j = 0; j < 8; ++j) s[j] += sn * fs[j];
    float4 bv0 = *(const float4*)(b2 + li * 8);
    float4 bv1 = *(const float4*)(b2 + li * 8 + 4);
    float4 o0 = make_float4(s[0] + bv0.x, s[1] + bv0.y, s[2] + bv0.z, s[3] + bv0.w);
    float4 o1 = make_float4(s[4] + bv1.x, s[5] + bv1.y, s[6] + bv1.z, s[7] + bv1.w);
    *(float4*)(OUT + (size_t)wid * FO + li * 8) = o0;
    *(float4*)(OUT + (size_t)wid * FO + li * 8 + 4) = o1;
  }
}

extern "C" void kernel_launch(void* const* d_in, const int* in_sizes, int n_in,
                              void* d_out, int out_size, void* d_ws, size_t ws_size,
                              hipStream_t stream) {
  const float* x  = (const float*)d_in[0];
  const int*   ei = (const int*)d_in[1];
  const float* ew = (const float*)d_in[2];
  const float* W1 = (const float*)d_in[3];
  const float* b1 = (const float*)d_in[4];
  const float* W2 = (const float*)d_in[5];
  const float* b2 = (const float*)d_in[6];
  float* out = (float*)d_out;

  const int N = in_sizes[0] / FIN;        // 100000
  const int E = in_sizes[2];              // 3200000
  const int* src = ei;
  const int* dst = ei + E;
  const int NBG = (N + 63) / 64;          // gemm1 tiles (1563)
  const int NBA = (E + EBLK - 1) / EBLK;  // A-phase blocks (391)
  const int NB  = (N + 255) / 256;        // buckets (391)
  const int L   = NB * NBA;               // gtable length (152,881)
  const int nsb = (L + 1023) / 1024;      // scan blocks (150, <=256)

  // workspace layout (16B-aligned slices), ~117MB total
  char* ws = (char*)d_ws;
  size_t off = 0;
  unsigned short* h1h = (unsigned short*)(ws + off); off += (size_t)N * FH * 2;  // fp16 h1
  unsigned short* h2h = (unsigned short*)(ws + off); off += (size_t)N * FO * 2;  // fp16 h2
  unsigned short* a1b = (unsigned short*)(ws + off); off += (size_t)N * FH * 2;  // bf16 a1
  int2*  edges  = (int2*) (ws + off); off += (size_t)E * 8;
  unsigned long long* bdw = (unsigned long long*)(ws + off); off += (size_t)E * 8;
  int*   gtable = (int*)  (ws + off); off += (((size_t)L * 4) + 15) & ~(size_t)15;
  int*   rowptr = (int*)  (ws + off); off += (((size_t)(N + 1) * 4) + 15) & ~(size_t)15;
  float* dinv   = (float*)(ws + off); off += (size_t)N * 4;
  int*   bsum   = (int*)  (ws + off); off += 1024;
  unsigned short* WT1 = (unsigned short*)(ws + off); off += (size_t)FH * FIN * 2;  // bf16 W1^T
  unsigned short* WT2 = (unsigned short*)(ws + off); off += (size_t)FO * FH * 2;   // bf16 W2^T

  // weight transpose + bf16 cvt (tiny, off critical path)
  prep_w_kernel<<<(FIN * FH + FH * FO + 255) / 256, 256, 0, stream>>>(W1, W2, WT1, WT2);
  // CSR build (LDS-atomic bucketed) + MFMA gemm1 fused
  a1hist_gemm1_kernel<<<NBA + NBG, 256, 0, stream>>>(dst, gtable, E, NBA, NB,
                                                     x, WT1, h1h, N, NBG);
  scan1i_kernel<<<nsb, 256, 0, stream>>>(gtable, bsum, L);
  scan2_kernel<<<1, 256, 0, stream>>>(bsum, nsb);
  scan3_kernel<<<(L + 255) / 256, 256, 0, stream>>>(gtable, bsum, L);
  a3_bucketize_kernel<<<NBA, 256, 0, stream>>>(src, dst, ew, gtable, bdw, E, NBA);
  b1_degree_kernel<<<NB, 256, 0, stream>>>(bdw, gtable, rowptr, dinv, E, NBA, NB, N);
  b2_scatter_kernel<<<NB, 256, 0, stream>>>(bdw, gtable, rowptr, dinv, edges,
                                            E, NBA, NB);
  // layers
  agg1_kernel<<<(N * 64 + 255) / 256, 256, 0, stream>>>(h1h, edges, rowptr,
                                                        dinv, b1, a1b, N);
  gemm2_kernel<<<(N + 63) / 64, 256, 0, stream>>>(a1b, WT2, h2h, N);
  agg2_kernel<<<(N * 64 + 255) / 256, 256, 0, stream>>>(h2h, edges, rowptr,
                                                        dinv, b2, out, N);
}

// Round 15
// 324.068 us; speedup vs baseline: 1.2365x; 1.1425x over previous
//
#include <hip/hip_runtime.h>
#include <hip/hip_bf16.h>
#include <hip/hip_fp16.h>

// GCN 2-layer encoder: N=100000 nodes, E=3.2M edges, Fin=256, Fh=128, Fo=64.
//   h1 = x@W1 ; a1 = relu(A@h1 + b1) ; h2 = a1@W2 ; out = A@h2 + b2
//
// R15: h1 stored FP8 e4m3 (HW v_cvt_pk fp8<->f32). R14 showed agg1 is
// L2-fill-BW-bound (111us flat across occupancy/MLP changes, FETCH 370MB):
// only byte reduction helps. 256B->128B per gathered row halves the
// dominant traffic. Error model: fp8 sigma 0.025 on h1~N(0,1), shrunk
// x0.16 (agg1) -> gemm2 -> x0.16 (agg2) => ~4e-3 max added at output vs
// 8.28e-3 threshold (current 1.95e-3). h2 stays fp16 (its error is
// un-smoothed). Rest identical to R14: MFMA gemm1+bucketed CSR build
// fused, MFMA gemm2, quarter/eighth-wave aggs, a1 bf16, W^T bf16.

#define FIN 256
#define FH  128
#define FO  64

#define EBLK 8192                     // edges per A-phase block (256 thr x 32)
#define WFX  33554432.0f              // 2^25 fixed-point degree scale
#define WFXI (1.0f / 33554432.0f)

typedef short s16x8 __attribute__((ext_vector_type(8)));
typedef float f32x4 __attribute__((ext_vector_type(4)));
typedef float f32x2 __attribute__((ext_vector_type(2)));

__device__ __forceinline__ unsigned int f2h(float f) {
  union { _Float16 h; unsigned short s; } c; c.h = (_Float16)f;  // RNE cvt
  return (unsigned int)c.s;
}
__device__ __forceinline__ unsigned int f2bf(float f) {
  union { float f; unsigned int i; } c; c.f = f;
  unsigned int i = c.i;
  return (i + 0x7FFFu + ((i >> 16) & 1u)) >> 16;  // RNE
}
// unpack uint4 of 8 fp16 -> 8 f32 via packed cvt (no shifts)
__device__ __forceinline__ void cvt8(const uint4& v, float* f) {
  const __half2* hp = (const __half2*)&v;
  #pragma unroll
  for (int j = 0; j < 4; ++j) {
    float2 t = __half22float2(hp[j]);
    f[2 * j] = t.x; f[2 * j + 1] = t.y;
  }
}
// unpack uint2 of 8 fp8(e4m3) -> 8 f32 via v_cvt_pk_f32_fp8
__device__ __forceinline__ void cvt8q(const uint2& v, float* f) {
  f32x2 t0 = __builtin_amdgcn_cvt_pk_f32_fp8((int)v.x, false);
  f32x2 t1 = __builtin_amdgcn_cvt_pk_f32_fp8((int)v.x, true);
  f32x2 t2 = __builtin_amdgcn_cvt_pk_f32_fp8((int)v.y, false);
  f32x2 t3 = __builtin_amdgcn_cvt_pk_f32_fp8((int)v.y, true);
  f[0] = t0[0]; f[1] = t0[1]; f[2] = t1[0]; f[3] = t1[1];
  f[4] = t2[0]; f[5] = t2[1]; f[6] = t3[0]; f[7] = t3[1];
}

// ---------------- prep: WT1[j][k]=bf16(W1[k][j]); WT2[j][k]=bf16(W2[k][j])
__global__ __launch_bounds__(256) void prep_w_kernel(
    const float* __restrict__ W1, const float* __restrict__ W2,
    unsigned short* __restrict__ WT1, unsigned short* __restrict__ WT2) {
  int i = blockIdx.x * 256 + threadIdx.x;
  if (i < FIN * FH) {
    int k = i >> 7, j = i & 127;
    WT1[j * FIN + k] = (unsigned short)f2bf(W1[i]);
  } else {
    int i2 = i - FIN * FH;
    if (i2 < FH * FO) {
      int k = i2 >> 6, j = i2 & 63;
      WT2[j * FH + k] = (unsigned short)f2bf(W2[i2]);
    }
  }
}

// ---------------- A1 hist (blocks [0,NBA)) + MFMA gemm1 (blocks [NBA,..))
// gemm1 writes h1 as fp8 e4m3
__global__ __launch_bounds__(256) void a1hist_gemm1_kernel(
    const int* __restrict__ dst, int* __restrict__ gtable, int E,
    int NBA, int NB,
    const float* __restrict__ X, const unsigned short* __restrict__ WT1,
    unsigned char* __restrict__ H1q, int N, int NBG) {
  __shared__ __align__(16) short XS[64 * 40];    // 64 rows x 32 k (bf16)
  __shared__ __align__(16) short WTS[128 * 40];  // 128 cols x 32 k (bf16)
  __shared__ unsigned int bh[392];
  int bid = blockIdx.x;
  int tid = threadIdx.x;
  if (bid < NBA) {
    // ---- bucket-histogram role
    for (int k = tid; k < NB; k += 256) bh[k] = 0u;
    __syncthreads();
    int e0 = bid * EBLK;
    #pragma unroll 4
    for (int it = 0; it < EBLK / 256; ++it) {
      int e = e0 + it * 256 + tid;
      if (e < E) atomicAdd(&bh[dst[e] >> 8], 1u);
    }
    __syncthreads();
    for (int k = tid; k < NB; k += 256)
      gtable[k * NBA + bid] = (int)bh[k];
    return;
  }
  int g = bid - NBA;
  if (g >= NBG) return;
  // ---- MFMA gemm1 role: H1q[64 rows,128 cols] fp8 = X @ W1 (bf16 MFMA)
  int row0 = g * 64;
  int wave = tid >> 6, lane = tid & 63;
  int lr = lane & 15, lq = lane >> 4;          // fragment row & k-octet
  f32x4 acc[8];
  #pragma unroll
  for (int c = 0; c < 8; ++c) acc[c] = (f32x4)(0.f);

  for (int k0 = 0; k0 < FIN; k0 += 32) {
    {  // stage XS: thread t -> row t>>2, koff (t&3)*8 ; f32 -> bf16
      int row = tid >> 2, koff = (tid & 3) * 8;
      int gr = row0 + row;
      float4 va = make_float4(0.f, 0.f, 0.f, 0.f), vb = va;
      if (gr < N) {
        va = *(const float4*)(X + (size_t)gr * FIN + k0 + koff);
        vb = *(const float4*)(X + (size_t)gr * FIN + k0 + koff + 4);
      }
      s16x8 hv;
      hv[0] = (short)f2bf(va.x); hv[1] = (short)f2bf(va.y);
      hv[2] = (short)f2bf(va.z); hv[3] = (short)f2bf(va.w);
      hv[4] = (short)f2bf(vb.x); hv[5] = (short)f2bf(vb.y);
      hv[6] = (short)f2bf(vb.z); hv[7] = (short)f2bf(vb.w);
      *(s16x8*)(&XS[row * 40 + koff]) = hv;
    }
    {  // stage WTS: thread t -> j t>>1, 16-half o (t&1)*16 (WT1 is bf16)
      int j = tid >> 1, o = (tid & 1) * 16;
      uint4 v0 = *(const uint4*)(WT1 + (size_t)j * FIN + k0 + o);
      uint4 v1 = *(const uint4*)(WT1 + (size_t)j * FIN + k0 + o + 8);
      *(uint4*)(&WTS[j * 40 + o]) = v0;
      *(uint4*)(&WTS[j * 40 + o + 8]) = v1;
    }
    __syncthreads();
    s16x8 af = *(const s16x8*)(&XS[(wave * 16 + lr) * 40 + lq * 8]);
    #pragma unroll
    for (int c = 0; c < 8; ++c) {
      s16x8 bf = *(const s16x8*)(&WTS[(c * 16 + lr) * 40 + lq * 8]);
      acc[c] = __builtin_amdgcn_mfma_f32_16x16x32_bf16(af, bf, acc[c], 0, 0, 0);
    }
    __syncthreads();
  }
  // epilogue: D row=(l>>4)*4+r (within wave's 16), col=c*16+(l&15); fp8 out
  int orow = row0 + wave * 16 + lq * 4;
  #pragma unroll
  for (int c = 0; c < 8; ++c) {
    #pragma unroll
    for (int r = 0; r < 4; ++r) {
      int gr = orow + r;
      if (gr < N) {
        int pk = __builtin_amdgcn_cvt_pk_fp8_f32(acc[c][r], acc[c][r], 0, false);
        H1q[(size_t)gr * FH + c * 16 + lr] = (unsigned char)(pk & 0xff);
      }
    }
  }
}

// ---------------- 3-phase exclusive scan, in-place on int array of length L
__global__ __launch_bounds__(256) void scan1i_kernel(
    int* __restrict__ arr, int* __restrict__ bsum, int L) {
  __shared__ int tot[256];
  int t = threadIdx.x;
  int base = blockIdx.x * 1024 + t * 4;
  int v0 = (base + 0 < L) ? arr[base + 0] : 0;
  int v1 = (base + 1 < L) ? arr[base + 1] : 0;
  int v2 = (base + 2 < L) ? arr[base + 2] : 0;
  int v3 = (base + 3 < L) ? arr[base + 3] : 0;
  int s = v0 + v1 + v2 + v3;
  tot[t] = s;
  __syncthreads();
  for (int off = 1; off < 256; off <<= 1) {
    int y = (t >= off) ? tot[t - off] : 0;
    __syncthreads();
    tot[t] += y;
    __syncthreads();
  }
  int p = tot[t] - s;  // exclusive within block
  if (t == 255) bsum[blockIdx.x] = tot[255];
  if (base + 0 < L) arr[base + 0] = p; p += v0;
  if (base + 1 < L) arr[base + 1] = p; p += v1;
  if (base + 2 < L) arr[base + 2] = p; p += v2;
  if (base + 3 < L) arr[base + 3] = p;
}

__global__ __launch_bounds__(256) void scan2_kernel(
    int* __restrict__ bsum, int nb) {
  __shared__ int buf[256];
  int t = threadIdx.x;
  int v = (t < nb) ? bsum[t] : 0;
  buf[t] = v;
  __syncthreads();
  for (int off = 1; off < 256; off <<= 1) {
    int y = (t >= off) ? buf[t - off] : 0;
    __syncthreads();
    buf[t] += y;
    __syncthreads();
  }
  if (t < nb) bsum[t] = buf[t] - v;  // exclusive
}

__global__ __launch_bounds__(256) void scan3_kernel(
    int* __restrict__ arr, const int* __restrict__ bsum, int L) {
  int i = blockIdx.x * 256 + threadIdx.x;
  if (i < L) arr[i] += bsum[i >> 10];
}

// ---------------- A3: bucketize edges -> bdw[pos] = {w(32) | l(8) | src(20)}
__global__ __launch_bounds__(256) void a3_bucketize_kernel(
    const int* __restrict__ src, const int* __restrict__ dst,
    const float* __restrict__ w, const int* __restrict__ gtable,
    unsigned long long* __restrict__ bdw, int E, int NBA) {
  __shared__ unsigned int bh[392];
  int bid = blockIdx.x;
  int tid = threadIdx.x;
  for (int k = tid; k < 392; k += 256) bh[k] = 0u;
  __syncthreads();
  int e0 = bid * EBLK;
  #pragma unroll 4
  for (int it = 0; it < EBLK / 256; ++it) {
    int e = e0 + it * 256 + tid;
    if (e < E) {
      int d = dst[e];
      int k = d >> 8;
      unsigned int l = (unsigned int)(d & 255);
      unsigned int r = atomicAdd(&bh[k], 1u);
      int pos = gtable[k * NBA + bid] + (int)r;
      unsigned int lo = (unsigned int)src[e] | (l << 20);
      unsigned long long v = ((unsigned long long)__float_as_uint(w[e]) << 32)
                           | (unsigned long long)lo;
      bdw[pos] = v;
    }
  }
}

// ---------------- B1: per-bucket degree + rowptr + dinv (LDS atomics)
__global__ __launch_bounds__(256) void b1_degree_kernel(
    const unsigned long long* __restrict__ bdw,
    const int* __restrict__ gtable, int* __restrict__ rowptr,
    float* __restrict__ dinv, int E, int NBA, int NB, int N) {
  __shared__ unsigned int lcnt[256];
  __shared__ unsigned int lwfx[256];
  __shared__ int sc[256];
  int k = blockIdx.x;
  int t = threadIdx.x;
  lcnt[t] = 0u; lwfx[t] = 0u;
  __syncthreads();
  int base = gtable[k * NBA];
  int end  = (k + 1 < NB) ? gtable[(k + 1) * NBA] : E;
  for (int i = base + t; i < end; i += 256) {
    unsigned long long v = bdw[i];
    unsigned int lo = (unsigned int)v;
    unsigned int l = (lo >> 20) & 0xFFu;
    float wv = __uint_as_float((unsigned int)(v >> 32));
    atomicAdd(&lcnt[l], 1u);
    atomicAdd(&lwfx[l], (unsigned int)(wv * WFX));
  }
  __syncthreads();
  int c = (int)lcnt[t];
  sc[t] = c;
  __syncthreads();
  for (int off = 1; off < 256; off <<= 1) {
    int y = (t >= off) ? sc[t - off] : 0;
    __syncthreads();
    sc[t] += y;
    __syncthreads();
  }
  int excl = sc[t] - c;
  int node = (k << 8) + t;
  if (node < N) {
    rowptr[node] = base + excl;
    float deg = (float)lwfx[t] * WFXI;
    dinv[node] = rsqrtf(1.0f + deg);
  }
  if (k == 0 && t == 0) rowptr[N] = E;
}

// ---------------- B2: per-bucket CSR scatter: edges[rowptr[d]+rank]={src,norm}
__global__ __launch_bounds__(256) void b2_scatter_kernel(
    const unsigned long long* __restrict__ bdw,
    const int* __restrict__ gtable, const int* __restrict__ rowptr,
    const float* __restrict__ dinv, int2* __restrict__ edges,
    int E, int NBA, int NB) {
  __shared__ unsigned int rcnt[256];
  int k = blockIdx.x;
  int t = threadIdx.x;
  rcnt[t] = 0u;
  __syncthreads();
  int base = gtable[k * NBA];
  int end  = (k + 1 < NB) ? gtable[(k + 1) * NBA] : E;
  for (int i = base + t; i < end; i += 256) {
    unsigned long long v = bdw[i];
    unsigned int lo = (unsigned int)v;
    int s = (int)(lo & 0xFFFFFu);
    unsigned int l = (lo >> 20) & 0xFFu;
    float wv = __uint_as_float((unsigned int)(v >> 32));
    unsigned int r = atomicAdd(&rcnt[l], 1u);
    int d = (k << 8) + (int)l;
    int pos = rowptr[d] + (int)r;
    float nm = dinv[s] * wv * dinv[d];
    edges[pos] = make_int2(s, __float_as_int(nm));
  }
}

// ---------------- MFMA GEMM2: H2h[N,64] fp16 = A1b[N,128] bf16 @ W2
__global__ __launch_bounds__(256) void gemm2_kernel(
    const unsigned short* __restrict__ A1b, const unsigned short* __restrict__ WT2,
    unsigned short* __restrict__ H2h, int N) {
  __shared__ __align__(16) short XS[64 * 40];   // 64 rows x 32 k
  __shared__ __align__(16) short WTS[64 * 40];  // 64 cols x 32 k
  int tid = threadIdx.x;
  int row0 = blockIdx.x * 64;
  int wave = tid >> 6, lane = tid & 63;
  int lr = lane & 15, lq = lane >> 4;
  f32x4 acc[4];
  #pragma unroll
  for (int c = 0; c < 4; ++c) acc[c] = (f32x4)(0.f);

  for (int k0 = 0; k0 < FH; k0 += 32) {
    {  // stage XS: row=t>>2, o=(t&3)*8 (A1b already bf16)
      int row = tid >> 2, o = (tid & 3) * 8;
      int gr = row0 + row;
      uint4 v = make_uint4(0u, 0u, 0u, 0u);
      if (gr < N) v = *(const uint4*)(A1b + (size_t)gr * FH + k0 + o);
      *(uint4*)(&XS[row * 40 + o]) = v;
    }
    {  // stage WTS: j=t>>2, o=(t&3)*8
      int j = tid >> 2, o = (tid & 3) * 8;
      uint4 v = *(const uint4*)(WT2 + (size_t)j * FH + k0 + o);
      *(uint4*)(&WTS[j * 40 + o]) = v;
    }
    __syncthreads();
    s16x8 af = *(const s16x8*)(&XS[(wave * 16 + lr) * 40 + lq * 8]);
    #pragma unroll
    for (int c = 0; c < 4; ++c) {
      s16x8 bf = *(const s16x8*)(&WTS[(c * 16 + lr) * 40 + lq * 8]);
      acc[c] = __builtin_amdgcn_mfma_f32_16x16x32_bf16(af, bf, acc[c], 0, 0, 0);
    }
    __syncthreads();
  }
  int orow = row0 + wave * 16 + lq * 4;
  #pragma unroll
  for (int c = 0; c < 4; ++c) {
    #pragma unroll
    for (int r = 0; r < 4; ++r) {
      int gr = orow + r;
      if (gr < N)
        H2h[(size_t)gr * FO + c * 16 + lr] = (unsigned short)f2h(acc[c][r]);
    }
  }
}

// ---------------- agg1: a1b = relu(A @ h1 + b1), 128 fp8 feats gathered
// quarter-wave per row: 16 lanes x 8B; 4 edges/wave x3 unroll = 12 in flight
__global__ __launch_bounds__(256) void agg1_kernel(
    const unsigned char* __restrict__ H1q, const int2* __restrict__ edges,
    const int* __restrict__ rowptr, const float* __restrict__ dinv,
    const float* __restrict__ b1, unsigned short* __restrict__ A1b, int N) {
  int wid = (blockIdx.x * 256 + threadIdx.x) >> 6;
  int lane = threadIdx.x & 63;
  if (wid >= N) return;
  int p0 = rowptr[wid], p1 = rowptr[wid + 1];
  int grp = lane >> 4, li = lane & 15;      // li covers feats li*8..+7
  const size_t rowoff = (size_t)li * 8;     // bytes (fp8)
  float a0[8], a1v[8], a2v[8];
  #pragma unroll
  for (int j = 0; j < 8; ++j) { a0[j] = 0.f; a1v[j] = 0.f; a2v[j] = 0.f; }

  int p = p0;
  for (; p + 12 <= p1; p += 12) {
    int2 e0 = edges[p + grp];
    int2 e1 = edges[p + 4 + grp];
    int2 e2 = edges[p + 8 + grp];
    uint2 h0 = *(const uint2*)(H1q + (size_t)e0.x * FH + rowoff);
    uint2 h1 = *(const uint2*)(H1q + (size_t)e1.x * FH + rowoff);
    uint2 h2 = *(const uint2*)(H1q + (size_t)e2.x * FH + rowoff);
    float n0 = __int_as_float(e0.y), n1 = __int_as_float(e1.y);
    float n2 = __int_as_float(e2.y);
    float f0[8], f1[8], f2[8];
    cvt8q(h0, f0); cvt8q(h1, f1); cvt8q(h2, f2);
    #pragma unroll
    for (int j = 0; j < 8; ++j) {
      a0[j] += n0 * f0[j];
      a1v[j] += n1 * f1[j];
      a2v[j] += n2 * f2[j];
    }
  }
  for (; p + 4 <= p1; p += 4) {
    int2 e0 = edges[p + grp];
    uint2 h0 = *(const uint2*)(H1q + (size_t)e0.x * FH + rowoff);
    float n0 = __int_as_float(e0.y);
    float f0[8];
    cvt8q(h0, f0);
    #pragma unroll
    for (int j = 0; j < 8; ++j) a0[j] += n0 * f0[j];
  }
  if (p < p1) {  // 1..3 leftover edges: masked
    int q = p + grp;
    int qi = (q < p1) ? q : p;
    int2 e0 = edges[qi];
    float n0 = (q < p1) ? __int_as_float(e0.y) : 0.f;
    uint2 h0 = *(const uint2*)(H1q + (size_t)e0.x * FH + rowoff);
    float f0[8];
    cvt8q(h0, f0);
    #pragma unroll
    for (int j = 0; j < 8; ++j) a0[j] += n0 * f0[j];
  }
  float s[8];
  #pragma unroll
  for (int j = 0; j < 8; ++j) {
    s[j] = (a0[j] + a1v[j]) + a2v[j];
    s[j] += __shfl_xor(s[j], 16);
    s[j] += __shfl_xor(s[j], 32);
  }
  if (lane < 16) {
    float di = dinv[wid], sn = di * di;
    uint2 hs = *(const uint2*)(H1q + (size_t)wid * FH + rowoff);
    float fs[8];
    cvt8q(hs, fs);
    #pragma unroll
    for (int j = 0; j < 8; ++j) s[j] += sn * fs[j];
    float4 bv0 = *(const float4*)(b1 + li * 8);
    float4 bv1 = *(const float4*)(b1 + li * 8 + 4);
    s[0] = fmaxf(s[0] + bv0.x, 0.f); s[1] = fmaxf(s[1] + bv0.y, 0.f);
    s[2] = fmaxf(s[2] + bv0.z, 0.f); s[3] = fmaxf(s[3] + bv0.w, 0.f);
    s[4] = fmaxf(s[4] + bv1.x, 0.f); s[5] = fmaxf(s[5] + bv1.y, 0.f);
    s[6] = fmaxf(s[6] + bv1.z, 0.f); s[7] = fmaxf(s[7] + bv1.w, 0.f);
    uint4 pk;
    pk.x = f2bf(s[0]) | (f2bf(s[1]) << 16);
    pk.y = f2bf(s[2]) | (f2bf(s[3]) << 16);
    pk.z = f2bf(s[4]) | (f2bf(s[5]) << 16);
    pk.w = f2bf(s[6]) | (f2bf(s[7]) << 16);
    *(uint4*)(A1b + (size_t)wid * FH + li * 8) = pk;
  }
}

// ---------------- agg2: out = A @ h2 + b2, 64 fp16 feats
// eighth-wave per row: 8 lanes x 16B; 8 edges/wave x2 unroll = 16 in flight
__global__ __launch_bounds__(256) void agg2_kernel(
    const unsigned short* __restrict__ H2h, const int2* __restrict__ edges,
    const int* __restrict__ rowptr, const float* __restrict__ dinv,
    const float* __restrict__ b2, float* __restrict__ OUT, int N) {
  int wid = (blockIdx.x * 256 + threadIdx.x) >> 6;
  int lane = threadIdx.x & 63;
  if (wid >= N) return;
  int p0 = rowptr[wid], p1 = rowptr[wid + 1];
  int grp = lane >> 3, li = lane & 7;       // li covers feats li*8..+7
  const size_t rowoff = (size_t)li * 8;
  float a0[8], a1v[8];
  #pragma unroll
  for (int j = 0; j < 8; ++j) { a0[j] = 0.f; a1v[j] = 0.f; }

  int p = p0;
  for (; p + 16 <= p1; p += 16) {
    int2 e0 = edges[p + grp];
    int2 e1 = edges[p + 8 + grp];
    uint4 h0 = *(const uint4*)(H2h + (size_t)e0.x * FO + rowoff);
    uint4 h1 = *(const uint4*)(H2h + (size_t)e1.x * FO + rowoff);
    float n0 = __int_as_float(e0.y), n1 = __int_as_float(e1.y);
    float f0[8], f1[8];
    cvt8(h0, f0); cvt8(h1, f1);
    #pragma unroll
    for (int j = 0; j < 8; ++j) {
      a0[j] += n0 * f0[j];
      a1v[j] += n1 * f1[j];
    }
  }
  for (; p + 8 <= p1; p += 8) {
    int2 e0 = edges[p + grp];
    uint4 h0 = *(const uint4*)(H2h + (size_t)e0.x * FO + rowoff);
    float n0 = __int_as_float(e0.y);
    float f0[8];
    cvt8(h0, f0);
    #pragma unroll
    for (int j = 0; j < 8; ++j) a0[j] += n0 * f0[j];
  }
  if (p < p1) {  // 1..7 leftover edges: masked
    int q = p + grp;
    int qi = (q < p1) ? q : p;
    int2 e0 = edges[qi];
    float n0 = (q < p1) ? __int_as_float(e0.y) : 0.f;
    uint4 h0 = *(const uint4*)(H2h + (size_t)e0.x * FO + rowoff);
    float f0[8];
    cvt8(h0, f0);
    #pragma unroll
    for (int j = 0; j < 8; ++j) a0[j] += n0 * f0[j];
  }
  float s[8];
  #pragma unroll
  for (int j = 0; j < 8; ++j) {
    s[j] = a0[j] + a1v[j];
    s[j] += __shfl_xor(s[j], 8);
    s[j] += __shfl_xor(s[j], 16);
    s[j] += __shfl_xor(s[j], 32);
  }
  if (lane < 8) {
    float di = dinv[wid], sn = di * di;
    uint4 hs = *(const uint4*)(H2h + (size_t)wid * FO + rowoff);
    float fs[8];
    cvt8(hs, fs);
    #pragma unroll
    for (int j = 0; j < 8; ++j) s[j] += sn * fs[j];
    float4 bv0 = *(const float4*)(b2 + li * 8);
    float4 bv1 = *(const float4*)(b2 + li * 8 + 4);
    float4 o0 = make_float4(s[0] + bv0.x, s[1] + bv0.y, s[2] + bv0.z, s[3] + bv0.w);
    float4 o1 = make_float4(s[4] + bv1.x, s[5] + bv1.y, s[6] + bv1.z, s[7] + bv1.w);
    *(float4*)(OUT + (size_t)wid * FO + li * 8) = o0;
    *(float4*)(OUT + (size_t)wid * FO + li * 8 + 4) = o1;
  }
}

extern "C" void kernel_launch(void* const* d_in, const int* in_sizes, int n_in,
                              void* d_out, int out_size, void* d_ws, size_t ws_size,
                              hipStream_t stream) {
  const float* x  = (const float*)d_in[0];
  const int*   ei = (const int*)d_in[1];
  const float* ew = (const float*)d_in[2];
  const float* W1 = (const float*)d_in[3];
  const float* b1 = (const float*)d_in[4];
  const float* W2 = (const float*)d_in[5];
  const float* b2 = (const float*)d_in[6];
  float* out = (float*)d_out;

  const int N = in_sizes[0] / FIN;        // 100000
  const int E = in_sizes[2];              // 3200000
  const int* src = ei;
  const int* dst = ei + E;
  const int NBG = (N + 63) / 64;          // gemm1 tiles (1563)
  const int NBA = (E + EBLK - 1) / EBLK;  // A-phase blocks (391)
  const int NB  = (N + 255) / 256;        // buckets (391)
  const int L   = NB * NBA;               // gtable length (152,881)
  const int nsb = (L + 1023) / 1024;      // scan blocks (150, <=256)

  // workspace layout (16B-aligned slices), ~104MB total
  char* ws = (char*)d_ws;
  size_t off = 0;
  unsigned char*  h1q = (unsigned char*)(ws + off);  off += (size_t)N * FH;      // fp8 h1
  unsigned short* h2h = (unsigned short*)(ws + off); off += (size_t)N * FO * 2;  // fp16 h2
  unsigned short* a1b = (unsigned short*)(ws + off); off += (size_t)N * FH * 2;  // bf16 a1
  int2*  edges  = (int2*) (ws + off); off += (size_t)E * 8;
  unsigned long long* bdw = (unsigned long long*)(ws + off); off += (size_t)E * 8;
  int*   gtable = (int*)  (ws + off); off += (((size_t)L * 4) + 15) & ~(size_t)15;
  int*   rowptr = (int*)  (ws + off); off += (((size_t)(N + 1) * 4) + 15) & ~(size_t)15;
  float* dinv   = (float*)(ws + off); off += (size_t)N * 4;
  int*   bsum   = (int*)  (ws + off); off += 1024;
  unsigned short* WT1 = (unsigned short*)(ws + off); off += (size_t)FH * FIN * 2;  // bf16 W1^T
  unsigned short* WT2 = (unsigned short*)(ws + off); off += (size_t)FO * FH * 2;   // bf16 W2^T

  // weight transpose + bf16 cvt (tiny, off critical path)
  prep_w_kernel<<<(FIN * FH + FH * FO + 255) / 256, 256, 0, stream>>>(W1, W2, WT1, WT2);
  // CSR build (LDS-atomic bucketed) + MFMA gemm1 fused
  a1hist_gemm1_kernel<<<NBA + NBG, 256, 0, stream>>>(dst, gtable, E, NBA, NB,
                                                     x, WT1, h1q, N, NBG);
  scan1i_kernel<<<nsb, 256, 0, stream>>>(gtable, bsum, L);
  scan2_kernel<<<1, 256, 0, stream>>>(bsum, nsb);
  scan3_kernel<<<(L + 255) / 256, 256, 0, stream>>>(gtable, bsum, L);
  a3_bucketize_kernel<<<NBA, 256, 0, stream>>>(src, dst, ew, gtable, bdw, E, NBA);
  b1_degree_kernel<<<NB, 256, 0, stream>>>(bdw, gtable, rowptr, dinv, E, NBA, NB, N);
  b2_scatter_kernel<<<NB, 256, 0, stream>>>(bdw, gtable, rowptr, dinv, edges,
                                            E, NBA, NB);
  // layers
  agg1_kernel<<<(N * 64 + 255) / 256, 256, 0, stream>>>(h1q, edges, rowptr,
                                                        dinv, b1, a1b, N);
  gemm2_kernel<<<(N + 63) / 64, 256, 0, stream>>>(a1b, WT2, h2h, N);
  agg2_kernel<<<(N * 64 + 255) / 256, 256, 0, stream>>>(h2h, edges, rowptr,
                                                        dinv, b2, out, N);
}

// Round 16
// 309.193 us; speedup vs baseline: 1.2960x; 1.0481x over previous
//
#include <hip/hip_runtime.h>
#include <hip/hip_bf16.h>
#include <hip/hip_fp16.h>

// GCN 2-layer encoder: N=100000 nodes, E=3.2M edges, Fin=256, Fh=128, Fo=64.
//   h1 = x@W1 ; a1 = relu(A@h1 + b1) ; h2 = a1@W2 ; out = A@h2 + b2
//
// R16: build kernels (a3 / b1 / b2) widened to 1024-thread blocks.
// R15 showed a3 at 90us with 13.7% occupancy: 391 blocks x 256 thr, each
// thread 32 SERIAL {LDS-atomic -> gtable read -> scattered write} chains
// (~300cy each) with ~6 waves/CU to hide them. 1024-thr blocks keep the
// same edge->block mapping (EBLK=8192, same ~21-edge write runs) but give
// 4x wave parallelism. B1/B2: edge loops stride 1024; 256-entry per-node
// LDS arrays + scan stay on lanes<256 (all threads execute barriers).
// Rest = R15: fp8 h1 (absmax 4.88e-3 vs 8.28e-3), MFMA gemms, bucketed CSR.

#define FIN 256
#define FH  128
#define FO  64

#define EBLK 8192                     // edges per A-phase block
#define WFX  33554432.0f              // 2^25 fixed-point degree scale
#define WFXI (1.0f / 33554432.0f)

typedef short s16x8 __attribute__((ext_vector_type(8)));
typedef float f32x4 __attribute__((ext_vector_type(4)));
typedef float f32x2 __attribute__((ext_vector_type(2)));

__device__ __forceinline__ unsigned int f2h(float f) {
  union { _Float16 h; unsigned short s; } c; c.h = (_Float16)f;  // RNE cvt
  return (unsigned int)c.s;
}
__device__ __forceinline__ unsigned int f2bf(float f) {
  union { float f; unsigned int i; } c; c.f = f;
  unsigned int i = c.i;
  return (i + 0x7FFFu + ((i >> 16) & 1u)) >> 16;  // RNE
}
// unpack uint4 of 8 fp16 -> 8 f32 via packed cvt (no shifts)
__device__ __forceinline__ void cvt8(const uint4& v, float* f) {
  const __half2* hp = (const __half2*)&v;
  #pragma unroll
  for (int j = 0; j < 4; ++j) {
    float2 t = __half22float2(hp[j]);
    f[2 * j] = t.x; f[2 * j + 1] = t.y;
  }
}
// unpack uint2 of 8 fp8(e4m3) -> 8 f32 via v_cvt_pk_f32_fp8
__device__ __forceinline__ void cvt8q(const uint2& v, float* f) {
  f32x2 t0 = __builtin_amdgcn_cvt_pk_f32_fp8((int)v.x, false);
  f32x2 t1 = __builtin_amdgcn_cvt_pk_f32_fp8((int)v.x, true);
  f32x2 t2 = __builtin_amdgcn_cvt_pk_f32_fp8((int)v.y, false);
  f32x2 t3 = __builtin_amdgcn_cvt_pk_f32_fp8((int)v.y, true);
  f[0] = t0[0]; f[1] = t0[1]; f[2] = t1[0]; f[3] = t1[1];
  f[4] = t2[0]; f[5] = t2[1]; f[6] = t3[0]; f[7] = t3[1];
}

// ---------------- prep: WT1[j][k]=bf16(W1[k][j]); WT2[j][k]=bf16(W2[k][j])
__global__ __launch_bounds__(256) void prep_w_kernel(
    const float* __restrict__ W1, const float* __restrict__ W2,
    unsigned short* __restrict__ WT1, unsigned short* __restrict__ WT2) {
  int i = blockIdx.x * 256 + threadIdx.x;
  if (i < FIN * FH) {
    int k = i >> 7, j = i & 127;
    WT1[j * FIN + k] = (unsigned short)f2bf(W1[i]);
  } else {
    int i2 = i - FIN * FH;
    if (i2 < FH * FO) {
      int k = i2 >> 6, j = i2 & 63;
      WT2[j * FH + k] = (unsigned short)f2bf(W2[i2]);
    }
  }
}

// ---------------- A1 hist (blocks [0,NBA)) + MFMA gemm1 (blocks [NBA,..))
// gemm1 writes h1 as fp8 e4m3
__global__ __launch_bounds__(256) void a1hist_gemm1_kernel(
    const int* __restrict__ dst, int* __restrict__ gtable, int E,
    int NBA, int NB,
    const float* __restrict__ X, const unsigned short* __restrict__ WT1,
    unsigned char* __restrict__ H1q, int N, int NBG) {
  __shared__ __align__(16) short XS[64 * 40];    // 64 rows x 32 k (bf16)
  __shared__ __align__(16) short WTS[128 * 40];  // 128 cols x 32 k (bf16)
  __shared__ unsigned int bh[392];
  int bid = blockIdx.x;
  int tid = threadIdx.x;
  if (bid < NBA) {
    // ---- bucket-histogram role
    for (int k = tid; k < NB; k += 256) bh[k] = 0u;
    __syncthreads();
    int e0 = bid * EBLK;
    #pragma unroll 4
    for (int it = 0; it < EBLK / 256; ++it) {
      int e = e0 + it * 256 + tid;
      if (e < E) atomicAdd(&bh[dst[e] >> 8], 1u);
    }
    __syncthreads();
    for (int k = tid; k < NB; k += 256)
      gtable[k * NBA + bid] = (int)bh[k];
    return;
  }
  int g = bid - NBA;
  if (g >= NBG) return;
  // ---- MFMA gemm1 role: H1q[64 rows,128 cols] fp8 = X @ W1 (bf16 MFMA)
  int row0 = g * 64;
  int wave = tid >> 6, lane = tid & 63;
  int lr = lane & 15, lq = lane >> 4;          // fragment row & k-octet
  f32x4 acc[8];
  #pragma unroll
  for (int c = 0; c < 8; ++c) acc[c] = (f32x4)(0.f);

  for (int k0 = 0; k0 < FIN; k0 += 32) {
    {  // stage XS: thread t -> row t>>2, koff (t&3)*8 ; f32 -> bf16
      int row = tid >> 2, koff = (tid & 3) * 8;
      int gr = row0 + row;
      float4 va = make_float4(0.f, 0.f, 0.f, 0.f), vb = va;
      if (gr < N) {
        va = *(const float4*)(X + (size_t)gr * FIN + k0 + koff);
        vb = *(const float4*)(X + (size_t)gr * FIN + k0 + koff + 4);
      }
      s16x8 hv;
      hv[0] = (short)f2bf(va.x); hv[1] = (short)f2bf(va.y);
      hv[2] = (short)f2bf(va.z); hv[3] = (short)f2bf(va.w);
      hv[4] = (short)f2bf(vb.x); hv[5] = (short)f2bf(vb.y);
      hv[6] = (short)f2bf(vb.z); hv[7] = (short)f2bf(vb.w);
      *(s16x8*)(&XS[row * 40 + koff]) = hv;
    }
    {  // stage WTS: thread t -> j t>>1, 16-half o (t&1)*16 (WT1 is bf16)
      int j = tid >> 1, o = (tid & 1) * 16;
      uint4 v0 = *(const uint4*)(WT1 + (size_t)j * FIN + k0 + o);
      uint4 v1 = *(const uint4*)(WT1 + (size_t)j * FIN + k0 + o + 8);
      *(uint4*)(&WTS[j * 40 + o]) = v0;
      *(uint4*)(&WTS[j * 40 + o + 8]) = v1;
    }
    __syncthreads();
    s16x8 af = *(const s16x8*)(&XS[(wave * 16 + lr) * 40 + lq * 8]);
    #pragma unroll
    for (int c = 0; c < 8; ++c) {
      s16x8 bf = *(const s16x8*)(&WTS[(c * 16 + lr) * 40 + lq * 8]);
      acc[c] = __builtin_amdgcn_mfma_f32_16x16x32_bf16(af, bf, acc[c], 0, 0, 0);
    }
    __syncthreads();
  }
  // epilogue: D row=(l>>4)*4+r (within wave's 16), col=c*16+(l&15); fp8 out
  int orow = row0 + wave * 16 + lq * 4;
  #pragma unroll
  for (int c = 0; c < 8; ++c) {
    #pragma unroll
    for (int r = 0; r < 4; ++r) {
      int gr = orow + r;
      if (gr < N) {
        int pk = __builtin_amdgcn_cvt_pk_fp8_f32(acc[c][r], acc[c][r], 0, false);
        H1q[(size_t)gr * FH + c * 16 + lr] = (unsigned char)(pk & 0xff);
      }
    }
  }
}

// ---------------- 3-phase exclusive scan, in-place on int array of length L
__global__ __launch_bounds__(256) void scan1i_kernel(
    int* __restrict__ arr, int* __restrict__ bsum, int L) {
  __shared__ int tot[256];
  int t = threadIdx.x;
  int base = blockIdx.x * 1024 + t * 4;
  int v0 = (base + 0 < L) ? arr[base + 0] : 0;
  int v1 = (base + 1 < L) ? arr[base + 1] : 0;
  int v2 = (base + 2 < L) ? arr[base + 2] : 0;
  int v3 = (base + 3 < L) ? arr[base + 3] : 0;
  int s = v0 + v1 + v2 + v3;
  tot[t] = s;
  __syncthreads();
  for (int off = 1; off < 256; off <<= 1) {
    int y = (t >= off) ? tot[t - off] : 0;
    __syncthreads();
    tot[t] += y;
    __syncthreads();
  }
  int p = tot[t] - s;  // exclusive within block
  if (t == 255) bsum[blockIdx.x] = tot[255];
  if (base + 0 < L) arr[base + 0] = p; p += v0;
  if (base + 1 < L) arr[base + 1] = p; p += v1;
  if (base + 2 < L) arr[base + 2] = p; p += v2;
  if (base + 3 < L) arr[base + 3] = p;
}

__global__ __launch_bounds__(256) void scan2_kernel(
    int* __restrict__ bsum, int nb) {
  __shared__ int buf[256];
  int t = threadIdx.x;
  int v = (t < nb) ? bsum[t] : 0;
  buf[t] = v;
  __syncthreads();
  for (int off = 1; off < 256; off <<= 1) {
    int y = (t >= off) ? buf[t - off] : 0;
    __syncthreads();
    buf[t] += y;
    __syncthreads();
  }
  if (t < nb) bsum[t] = buf[t] - v;  // exclusive
}

__global__ __launch_bounds__(256) void scan3_kernel(
    int* __restrict__ arr, const int* __restrict__ bsum, int L) {
  int i = blockIdx.x * 256 + threadIdx.x;
  if (i < L) arr[i] += bsum[i >> 10];
}

// ---------------- A3: bucketize edges -> bdw[pos] = {w(32) | l(8) | src(20)}
// 1024-thread blocks: 8 serial iters/thread (was 32) -> 4x wave parallelism
__global__ __launch_bounds__(1024) void a3_bucketize_kernel(
    const int* __restrict__ src, const int* __restrict__ dst,
    const float* __restrict__ w, const int* __restrict__ gtable,
    unsigned long long* __restrict__ bdw, int E, int NBA) {
  __shared__ unsigned int bh[392];
  int bid = blockIdx.x;
  int tid = threadIdx.x;
  for (int k = tid; k < 392; k += 1024) bh[k] = 0u;
  __syncthreads();
  int e0 = bid * EBLK;
  #pragma unroll 2
  for (int it = 0; it < EBLK / 1024; ++it) {
    int e = e0 + it * 1024 + tid;
    if (e < E) {
      int d = dst[e];
      int k = d >> 8;
      unsigned int l = (unsigned int)(d & 255);
      unsigned int r = atomicAdd(&bh[k], 1u);
      int pos = gtable[k * NBA + bid] + (int)r;
      unsigned int lo = (unsigned int)src[e] | (l << 20);
      unsigned long long v = ((unsigned long long)__float_as_uint(w[e]) << 32)
                           | (unsigned long long)lo;
      bdw[pos] = v;
    }
  }
}

// ---------------- B1: per-bucket degree + rowptr + dinv (LDS atomics)
// 1024 threads: edge loop strides 1024; scan on lanes<256
__global__ __launch_bounds__(1024) void b1_degree_kernel(
    const unsigned long long* __restrict__ bdw,
    const int* __restrict__ gtable, int* __restrict__ rowptr,
    float* __restrict__ dinv, int E, int NBA, int NB, int N) {
  __shared__ unsigned int lcnt[256];
  __shared__ unsigned int lwfx[256];
  __shared__ int sc[256];
  int k = blockIdx.x;
  int t = threadIdx.x;
  if (t < 256) { lcnt[t] = 0u; lwfx[t] = 0u; }
  __syncthreads();
  int base = gtable[k * NBA];
  int end  = (k + 1 < NB) ? gtable[(k + 1) * NBA] : E;
  for (int i = base + t; i < end; i += 1024) {
    unsigned long long v = bdw[i];
    unsigned int lo = (unsigned int)v;
    unsigned int l = (lo >> 20) & 0xFFu;
    float wv = __uint_as_float((unsigned int)(v >> 32));
    atomicAdd(&lcnt[l], 1u);
    atomicAdd(&lwfx[l], (unsigned int)(wv * WFX));
  }
  __syncthreads();
  int c = 0;
  if (t < 256) { c = (int)lcnt[t]; sc[t] = c; }
  __syncthreads();
  for (int off = 1; off < 256; off <<= 1) {
    int y = (t >= off && t < 256) ? sc[t - off] : 0;
    __syncthreads();
    if (t < 256) sc[t] += y;
    __syncthreads();
  }
  if (t < 256) {
    int excl = sc[t] - c;
    int node = (k << 8) + t;
    if (node < N) {
      rowptr[node] = base + excl;
      float deg = (float)lwfx[t] * WFXI;
      dinv[node] = rsqrtf(1.0f + deg);
    }
  }
  if (k == 0 && t == 0) rowptr[N] = E;
}

// ---------------- B2: per-bucket CSR scatter: edges[rowptr[d]+rank]={src,norm}
// 1024 threads: edge loop strides 1024
__global__ __launch_bounds__(1024) void b2_scatter_kernel(
    const unsigned long long* __restrict__ bdw,
    const int* __restrict__ gtable, const int* __restrict__ rowptr,
    const float* __restrict__ dinv, int2* __restrict__ edges,
    int E, int NBA, int NB) {
  __shared__ unsigned int rcnt[256];
  int k = blockIdx.x;
  int t = threadIdx.x;
  if (t < 256) rcnt[t] = 0u;
  __syncthreads();
  int base = gtable[k * NBA];
  int end  = (k + 1 < NB) ? gtable[(k + 1) * NBA] : E;
  for (int i = base + t; i < end; i += 1024) {
    unsigned long long v = bdw[i];
    unsigned int lo = (unsigned int)v;
    int s = (int)(lo & 0xFFFFFu);
    unsigned int l = (lo >> 20) & 0xFFu;
    float wv = __uint_as_float((unsigned int)(v >> 32));
    unsigned int r = atomicAdd(&rcnt[l], 1u);
    int d = (k << 8) + (int)l;
    int pos = rowptr[d] + (int)r;
    float nm = dinv[s] * wv * dinv[d];
    edges[pos] = make_int2(s, __float_as_int(nm));
  }
}

// ---------------- MFMA GEMM2: H2h[N,64] fp16 = A1b[N,128] bf16 @ W2
__global__ __launch_bounds__(256) void gemm2_kernel(
    const unsigned short* __restrict__ A1b, const unsigned short* __restrict__ WT2,
    unsigned short* __restrict__ H2h, int N) {
  __shared__ __align__(16) short XS[64 * 40];   // 64 rows x 32 k
  __shared__ __align__(16) short WTS[64 * 40];  // 64 cols x 32 k
  int tid = threadIdx.x;
  int row0 = blockIdx.x * 64;
  int wave = tid >> 6, lane = tid & 63;
  int lr = lane & 15, lq = lane >> 4;
  f32x4 acc[4];
  #pragma unroll
  for (int c = 0; c < 4; ++c) acc[c] = (f32x4)(0.f);

  for (int k0 = 0; k0 < FH; k0 += 32) {
    {  // stage XS: row=t>>2, o=(t&3)*8 (A1b already bf16)
      int row = tid >> 2, o = (tid & 3) * 8;
      int gr = row0 + row;
      uint4 v = make_uint4(0u, 0u, 0u, 0u);
      if (gr < N) v = *(const uint4*)(A1b + (size_t)gr * FH + k0 + o);
      *(uint4*)(&XS[row * 40 + o]) = v;
    }
    {  // stage WTS: j=t>>2, o=(t&3)*8
      int j = tid >> 2, o = (tid & 3) * 8;
      uint4 v = *(const uint4*)(WT2 + (size_t)j * FH + k0 + o);
      *(uint4*)(&WTS[j * 40 + o]) = v;
    }
    __syncthreads();
    s16x8 af = *(const s16x8*)(&XS[(wave * 16 + lr) * 40 + lq * 8]);
    #pragma unroll
    for (int c = 0; c < 4; ++c) {
      s16x8 bf = *(const s16x8*)(&WTS[(c * 16 + lr) * 40 + lq * 8]);
      acc[c] = __builtin_amdgcn_mfma_f32_16x16x32_bf16(af, bf, acc[c], 0, 0, 0);
    }
    __syncthreads();
  }
  int orow = row0 + wave * 16 + lq * 4;
  #pragma unroll
  for (int c = 0; c < 4; ++c) {
    #pragma unroll
    for (int r = 0; r < 4; ++r) {
      int gr = orow + r;
      if (gr < N)
        H2h[(size_t)gr * FO + c * 16 + lr] = (unsigned short)f2h(acc[c][r]);
    }
  }
}

// ---------------- agg1: a1b = relu(A @ h1 + b1), 128 fp8 feats gathered
// quarter-wave per row: 16 lanes x 8B; 4 edges/wave x3 unroll = 12 in flight
__global__ __launch_bounds__(256) void agg1_kernel(
    const unsigned char* __restrict__ H1q, const int2* __restrict__ edges,
    const int* __restrict__ rowptr, const float* __restrict__ dinv,
    const float* __restrict__ b1, unsigned short* __restrict__ A1b, int N) {
  int wid = (blockIdx.x * 256 + threadIdx.x) >> 6;
  int lane = threadIdx.x & 63;
  if (wid >= N) return;
  int p0 = rowptr[wid], p1 = rowptr[wid + 1];
  int grp = lane >> 4, li = lane & 15;      // li covers feats li*8..+7
  const size_t rowoff = (size_t)li * 8;     // bytes (fp8)
  float a0[8], a1v[8], a2v[8];
  #pragma unroll
  for (int j = 0; j < 8; ++j) { a0[j] = 0.f; a1v[j] = 0.f; a2v[j] = 0.f; }

  int p = p0;
  for (; p + 12 <= p1; p += 12) {
    int2 e0 = edges[p + grp];
    int2 e1 = edges[p + 4 + grp];
    int2 e2 = edges[p + 8 + grp];
    uint2 h0 = *(const uint2*)(H1q + (size_t)e0.x * FH + rowoff);
    uint2 h1 = *(const uint2*)(H1q + (size_t)e1.x * FH + rowoff);
    uint2 h2 = *(const uint2*)(H1q + (size_t)e2.x * FH + rowoff);
    float n0 = __int_as_float(e0.y), n1 = __int_as_float(e1.y);
    float n2 = __int_as_float(e2.y);
    float f0[8], f1[8], f2[8];
    cvt8q(h0, f0); cvt8q(h1, f1); cvt8q(h2, f2);
    #pragma unroll
    for (int j = 0; j < 8; ++j) {
      a0[j] += n0 * f0[j];
      a1v[j] += n1 * f1[j];
      a2v[j] += n2 * f2[j];
    }
  }
  for (; p + 4 <= p1; p += 4) {
    int2 e0 = edges[p + grp];
    uint2 h0 = *(const uint2*)(H1q + (size_t)e0.x * FH + rowoff);
    float n0 = __int_as_float(e0.y);
    float f0[8];
    cvt8q(h0, f0);
    #pragma unroll
    for (int j = 0; j < 8; ++j) a0[j] += n0 * f0[j];
  }
  if (p < p1) {  // 1..3 leftover edges: masked
    int q = p + grp;
    int qi = (q < p1) ? q : p;
    int2 e0 = edges[qi];
    float n0 = (q < p1) ? __int_as_float(e0.y) : 0.f;
    uint2 h0 = *(const uint2*)(H1q + (size_t)e0.x * FH + rowoff);
    float f0[8];
    cvt8q(h0, f0);
    #pragma unroll
    for (int j = 0; j < 8; ++j) a0[j] += n0 * f0[j];
  }
  float s[8];
  #pragma unroll
  for (int j = 0; j < 8; ++j) {
    s[j] = (a0[j] + a1v[j]) + a2v[j];
    s[j] += __shfl_xor(s[j], 16);
    s[j] += __shfl_xor(s[j], 32);
  }
  if (lane < 16) {
    float di = dinv[wid], sn = di * di;
    uint2 hs = *(const uint2*)(H1q + (size_t)wid * FH + rowoff);
    float fs[8];
    cvt8q(hs, fs);
    #pragma unroll
    for (int j = 0; j < 8; ++j) s[j] += sn * fs[j];
    float4 bv0 = *(const float4*)(b1 + li * 8);
    float4 bv1 = *(const float4*)(b1 + li * 8 + 4);
    s[0] = fmaxf(s[0] + bv0.x, 0.f); s[1] = fmaxf(s[1] + bv0.y, 0.f);
    s[2] = fmaxf(s[2] + bv0.z, 0.f); s[3] = fmaxf(s[3] + bv0.w, 0.f);
    s[4] = fmaxf(s[4] + bv1.x, 0.f); s[5] = fmaxf(s[5] + bv1.y, 0.f);
    s[6] = fmaxf(s[6] + bv1.z, 0.f); s[7] = fmaxf(s[7] + bv1.w, 0.f);
    uint4 pk;
    pk.x = f2bf(s[0]) | (f2bf(s[1]) << 16);
    pk.y = f2bf(s[2]) | (f2bf(s[3]) << 16);
    pk.z = f2bf(s[4]) | (f2bf(s[5]) << 16);
    pk.w = f2bf(s[6]) | (f2bf(s[7]) << 16);
    *(uint4*)(A1b + (size_t)wid * FH + li * 8) = pk;
  }
}

// ---------------- agg2: out = A @ h2 + b2, 64 fp16 feats
// eighth-wave per row: 8 lanes x 16B; 8 edges/wave x2 unroll = 16 in flight
__global__ __launch_bounds__(256) void agg2_kernel(
    const unsigned short* __restrict__ H2h, const int2* __restrict__ edges,
    const int* __restrict__ rowptr, const float* __restrict__ dinv,
    const float* __restrict__ b2, float* __restrict__ OUT, int N) {
  int wid = (blockIdx.x * 256 + threadIdx.x) >> 6;
  int lane = threadIdx.x & 63;
  if (wid >= N) return;
  int p0 = rowptr[wid], p1 = rowptr[wid + 1];
  int grp = lane >> 3, li = lane & 7;       // li covers feats li*8..+7
  const size_t rowoff = (size_t)li * 8;
  float a0[8], a1v[8];
  #pragma unroll
  for (int j = 0; j < 8; ++j) { a0[j] = 0.f; a1v[j] = 0.f; }

  int p = p0;
  for (; p + 16 <= p1; p += 16) {
    int2 e0 = edges[p + grp];
    int2 e1 = edges[p + 8 + grp];
    uint4 h0 = *(const uint4*)(H2h + (size_t)e0.x * FO + rowoff);
    uint4 h1 = *(const uint4*)(H2h + (size_t)e1.x * FO + rowoff);
    float n0 = __int_as_float(e0.y), n1 = __int_as_float(e1.y);
    float f0[8], f1[8];
    cvt8(h0, f0); cvt8(h1, f1);
    #pragma unroll
    for (int j = 0; j < 8; ++j) {
      a0[j] += n0 * f0[j];
      a1v[j] += n1 * f1[j];
    }
  }
  for (; p + 8 <= p1; p += 8) {
    int2 e0 = edges[p + grp];
    uint4 h0 = *(const uint4*)(H2h + (size_t)e0.x * FO + rowoff);
    float n0 = __int_as_float(e0.y);
    float f0[8];
    cvt8(h0, f0);
    #pragma unroll
    for (int j = 0; j < 8; ++j) a0[j] += n0 * f0[j];
  }
  if (p < p1) {  // 1..7 leftover edges: masked
    int q = p + grp;
    int qi = (q < p1) ? q : p;
    int2 e0 = edges[qi];
    float n0 = (q < p1) ? __int_as_float(e0.y) : 0.f;
    uint4 h0 = *(const uint4*)(H2h + (size_t)e0.x * FO + rowoff);
    float f0[8];
    cvt8(h0, f0);
    #pragma unroll
    for (int j = 0; j < 8; ++j) a0[j] += n0 * f0[j];
  }
  float s[8];
  #pragma unroll
  for (int j = 0; j < 8; ++j) {
    s[j] = a0[j] + a1v[j];
    s[j] += __shfl_xor(s[j], 8);
    s[j] += __shfl_xor(s[j], 16);
    s[j] += __shfl_xor(s[j], 32);
  }
  if (lane < 8) {
    float di = dinv[wid], sn = di * di;
    uint4 hs = *(const uint4*)(H2h + (size_t)wid * FO + rowoff);
    float fs[8];
    cvt8(hs, fs);
    #pragma unroll
    for (int j = 0; j < 8; ++j) s[j] += sn * fs[j];
    float4 bv0 = *(const float4*)(b2 + li * 8);
    float4 bv1 = *(const float4*)(b2 + li * 8 + 4);
    float4 o0 = make_float4(s[0] + bv0.x, s[1] + bv0.y, s[2] + bv0.z, s[3] + bv0.w);
    float4 o1 = make_float4(s[4] + bv1.x, s[5] + bv1.y, s[6] + bv1.z, s[7] + bv1.w);
    *(float4*)(OUT + (size_t)wid * FO + li * 8) = o0;
    *(float4*)(OUT + (size_t)wid * FO + li * 8 + 4) = o1;
  }
}

extern "C" void kernel_launch(void* const* d_in, const int* in_sizes, int n_in,
                              void* d_out, int out_size, void* d_ws, size_t ws_size,
                              hipStream_t stream) {
  const float* x  = (const float*)d_in[0];
  const int*   ei = (const int*)d_in[1];
  const float* ew = (const float*)d_in[2];
  const float* W1 = (const float*)d_in[3];
  const float* b1 = (const float*)d_in[4];
  const float* W2 = (const float*)d_in[5];
  const float* b2 = (const float*)d_in[6];
  float* out = (float*)d_out;

  const int N = in_sizes[0] / FIN;        // 100000
  const int E = in_sizes[2];              // 3200000
  const int* src = ei;
  const int* dst = ei + E;
  const int NBG = (N + 63) / 64;          // gemm1 tiles (1563)
  const int NBA = (E + EBLK - 1) / EBLK;  // A-phase blocks (391)
  const int NB  = (N + 255) / 256;        // buckets (391)
  const int L   = NB * NBA;               // gtable length (152,881)
  const int nsb = (L + 1023) / 1024;      // scan blocks (150, <=256)

  // workspace layout (16B-aligned slices), ~104MB total
  char* ws = (char*)d_ws;
  size_t off = 0;
  unsigned char*  h1q = (unsigned char*)(ws + off);  off += (size_t)N * FH;      // fp8 h1
  unsigned short* h2h = (unsigned short*)(ws + off); off += (size_t)N * FO * 2;  // fp16 h2
  unsigned short* a1b = (unsigned short*)(ws + off); off += (size_t)N * FH * 2;  // bf16 a1
  int2*  edges  = (int2*) (ws + off); off += (size_t)E * 8;
  unsigned long long* bdw = (unsigned long long*)(ws + off); off += (size_t)E * 8;
  int*   gtable = (int*)  (ws + off); off += (((size_t)L * 4) + 15) & ~(size_t)15;
  int*   rowptr = (int*)  (ws + off); off += (((size_t)(N + 1) * 4) + 15) & ~(size_t)15;
  float* dinv   = (float*)(ws + off); off += (size_t)N * 4;
  int*   bsum   = (int*)  (ws + off); off += 1024;
  unsigned short* WT1 = (unsigned short*)(ws + off); off += (size_t)FH * FIN * 2;  // bf16 W1^T
  unsigned short* WT2 = (unsigned short*)(ws + off); off += (size_t)FO * FH * 2;   // bf16 W2^T

  // weight transpose + bf16 cvt (tiny, off critical path)
  prep_w_kernel<<<(FIN * FH + FH * FO + 255) / 256, 256, 0, stream>>>(W1, W2, WT1, WT2);
  // CSR build (LDS-atomic bucketed) + MFMA gemm1 fused
  a1hist_gemm1_kernel<<<NBA + NBG, 256, 0, stream>>>(dst, gtable, E, NBA, NB,
                                                     x, WT1, h1q, N, NBG);
  scan1i_kernel<<<nsb, 256, 0, stream>>>(gtable, bsum, L);
  scan2_kernel<<<1, 256, 0, stream>>>(bsum, nsb);
  scan3_kernel<<<(L + 255) / 256, 256, 0, stream>>>(gtable, bsum, L);
  a3_bucketize_kernel<<<NBA, 1024, 0, stream>>>(src, dst, ew, gtable, bdw, E, NBA);
  b1_degree_kernel<<<NB, 1024, 0, stream>>>(bdw, gtable, rowptr, dinv, E, NBA, NB, N);
  b2_scatter_kernel<<<NB, 1024, 0, stream>>>(bdw, gtable, rowptr, dinv, edges,
                                             E, NBA, NB);
  // layers
  agg1_kernel<<<(N * 64 + 255) / 256, 256, 0, stream>>>(h1q, edges, rowptr,
                                                        dinv, b1, a1b, N);
  gemm2_kernel<<<(N + 63) / 64, 256, 0, stream>>>(a1b, WT2, h2h, N);
  agg2_kernel<<<(N * 64 + 255) / 256, 256, 0, stream>>>(h2h, edges, rowptr,
                                                        dinv, b2, out, N);
}

// Round 17
// 308.495 us; speedup vs baseline: 1.2989x; 1.0023x over previous
//
#include <hip/hip_runtime.h>
#include <hip/hip_bf16.h>
#include <hip/hip_fp16.h>

// GCN 2-layer encoder: N=100000 nodes, E=3.2M edges, Fin=256, Fh=128, Fo=64.
//   h1 = x@W1 ; a1 = relu(A@h1 + b1) ; h2 = a1@W2 ; out = A@h2 + b2
//
// R17: (a) EBLK 8192->2048: a3's serial {LDS-atomic -> gtable -> write}
// chain per thread drops 8->2 (R16 showed a3 chain-latency-bound: 81us at
// 44% occupancy, VALU 1.7%). gtable grows to 611K entries -> scan widened
// to 4096/block. (b) b2 fused into b1 ("b12"): pass2 re-reads the bucket's
// bdw L2-hot and writes CSR directly; edges carry {src, w*dinv[dst]} and
// aggs multiply dinv[src] at gather time (dinv 400KB, L2-resident).
// Rest = R16: fp8 h1, MFMA gemms, LDS-atomic bucketed CSR, 1024-thr build.

#define FIN 256
#define FH  128
#define FO  64

#define EBLK 2048                     // edges per A-phase block
#define WFX  33554432.0f              // 2^25 fixed-point degree scale
#define WFXI (1.0f / 33554432.0f)

typedef short s16x8 __attribute__((ext_vector_type(8)));
typedef float f32x4 __attribute__((ext_vector_type(4)));
typedef float f32x2 __attribute__((ext_vector_type(2)));

__device__ __forceinline__ unsigned int f2h(float f) {
  union { _Float16 h; unsigned short s; } c; c.h = (_Float16)f;  // RNE cvt
  return (unsigned int)c.s;
}
__device__ __forceinline__ unsigned int f2bf(float f) {
  union { float f; unsigned int i; } c; c.f = f;
  unsigned int i = c.i;
  return (i + 0x7FFFu + ((i >> 16) & 1u)) >> 16;  // RNE
}
// unpack uint4 of 8 fp16 -> 8 f32 via packed cvt (no shifts)
__device__ __forceinline__ void cvt8(const uint4& v, float* f) {
  const __half2* hp = (const __half2*)&v;
  #pragma unroll
  for (int j = 0; j < 4; ++j) {
    float2 t = __half22float2(hp[j]);
    f[2 * j] = t.x; f[2 * j + 1] = t.y;
  }
}
// unpack uint2 of 8 fp8(e4m3) -> 8 f32 via v_cvt_pk_f32_fp8
__device__ __forceinline__ void cvt8q(const uint2& v, float* f) {
  f32x2 t0 = __builtin_amdgcn_cvt_pk_f32_fp8((int)v.x, false);
  f32x2 t1 = __builtin_amdgcn_cvt_pk_f32_fp8((int)v.x, true);
  f32x2 t2 = __builtin_amdgcn_cvt_pk_f32_fp8((int)v.y, false);
  f32x2 t3 = __builtin_amdgcn_cvt_pk_f32_fp8((int)v.y, true);
  f[0] = t0[0]; f[1] = t0[1]; f[2] = t1[0]; f[3] = t1[1];
  f[4] = t2[0]; f[5] = t2[1]; f[6] = t3[0]; f[7] = t3[1];
}

// ---------------- prep: WT1[j][k]=bf16(W1[k][j]); WT2[j][k]=bf16(W2[k][j])
__global__ __launch_bounds__(256) void prep_w_kernel(
    const float* __restrict__ W1, const float* __restrict__ W2,
    unsigned short* __restrict__ WT1, unsigned short* __restrict__ WT2) {
  int i = blockIdx.x * 256 + threadIdx.x;
  if (i < FIN * FH) {
    int k = i >> 7, j = i & 127;
    WT1[j * FIN + k] = (unsigned short)f2bf(W1[i]);
  } else {
    int i2 = i - FIN * FH;
    if (i2 < FH * FO) {
      int k = i2 >> 6, j = i2 & 63;
      WT2[j * FH + k] = (unsigned short)f2bf(W2[i2]);
    }
  }
}

// ---------------- A1 hist (blocks [0,NBA)) + MFMA gemm1 (blocks [NBA,..))
// gemm1 writes h1 as fp8 e4m3
__global__ __launch_bounds__(256) void a1hist_gemm1_kernel(
    const int* __restrict__ dst, int* __restrict__ gtable, int E,
    int NBA, int NB,
    const float* __restrict__ X, const unsigned short* __restrict__ WT1,
    unsigned char* __restrict__ H1q, int N, int NBG) {
  __shared__ __align__(16) short XS[64 * 40];    // 64 rows x 32 k (bf16)
  __shared__ __align__(16) short WTS[128 * 40];  // 128 cols x 32 k (bf16)
  __shared__ unsigned int bh[392];
  int bid = blockIdx.x;
  int tid = threadIdx.x;
  if (bid < NBA) {
    // ---- bucket-histogram role (EBLK=2048: 8 atomic iters, no readback)
    for (int k = tid; k < NB; k += 256) bh[k] = 0u;
    __syncthreads();
    int e0 = bid * EBLK;
    #pragma unroll 4
    for (int it = 0; it < EBLK / 256; ++it) {
      int e = e0 + it * 256 + tid;
      if (e < E) atomicAdd(&bh[dst[e] >> 8], 1u);
    }
    __syncthreads();
    for (int k = tid; k < NB; k += 256)
      gtable[k * NBA + bid] = (int)bh[k];
    return;
  }
  int g = bid - NBA;
  if (g >= NBG) return;
  // ---- MFMA gemm1 role: H1q[64 rows,128 cols] fp8 = X @ W1 (bf16 MFMA)
  int row0 = g * 64;
  int wave = tid >> 6, lane = tid & 63;
  int lr = lane & 15, lq = lane >> 4;          // fragment row & k-octet
  f32x4 acc[8];
  #pragma unroll
  for (int c = 0; c < 8; ++c) acc[c] = (f32x4)(0.f);

  for (int k0 = 0; k0 < FIN; k0 += 32) {
    {  // stage XS: thread t -> row t>>2, koff (t&3)*8 ; f32 -> bf16
      int row = tid >> 2, koff = (tid & 3) * 8;
      int gr = row0 + row;
      float4 va = make_float4(0.f, 0.f, 0.f, 0.f), vb = va;
      if (gr < N) {
        va = *(const float4*)(X + (size_t)gr * FIN + k0 + koff);
        vb = *(const float4*)(X + (size_t)gr * FIN + k0 + koff + 4);
      }
      s16x8 hv;
      hv[0] = (short)f2bf(va.x); hv[1] = (short)f2bf(va.y);
      hv[2] = (short)f2bf(va.z); hv[3] = (short)f2bf(va.w);
      hv[4] = (short)f2bf(vb.x); hv[5] = (short)f2bf(vb.y);
      hv[6] = (short)f2bf(vb.z); hv[7] = (short)f2bf(vb.w);
      *(s16x8*)(&XS[row * 40 + koff]) = hv;
    }
    {  // stage WTS: thread t -> j t>>1, 16-half o (t&1)*16 (WT1 is bf16)
      int j = tid >> 1, o = (tid & 1) * 16;
      uint4 v0 = *(const uint4*)(WT1 + (size_t)j * FIN + k0 + o);
      uint4 v1 = *(const uint4*)(WT1 + (size_t)j * FIN + k0 + o + 8);
      *(uint4*)(&WTS[j * 40 + o]) = v0;
      *(uint4*)(&WTS[j * 40 + o + 8]) = v1;
    }
    __syncthreads();
    s16x8 af = *(const s16x8*)(&XS[(wave * 16 + lr) * 40 + lq * 8]);
    #pragma unroll
    for (int c = 0; c < 8; ++c) {
      s16x8 bf = *(const s16x8*)(&WTS[(c * 16 + lr) * 40 + lq * 8]);
      acc[c] = __builtin_amdgcn_mfma_f32_16x16x32_bf16(af, bf, acc[c], 0, 0, 0);
    }
    __syncthreads();
  }
  // epilogue: D row=(l>>4)*4+r (within wave's 16), col=c*16+(l&15); fp8 out
  int orow = row0 + wave * 16 + lq * 4;
  #pragma unroll
  for (int c = 0; c < 8; ++c) {
    #pragma unroll
    for (int r = 0; r < 4; ++r) {
      int gr = orow + r;
      if (gr < N) {
        int pk = __builtin_amdgcn_cvt_pk_fp8_f32(acc[c][r], acc[c][r], 0, false);
        H1q[(size_t)gr * FH + c * 16 + lr] = (unsigned char)(pk & 0xff);
      }
    }
  }
}

// ---------------- 3-phase exclusive scan, in-place, 4096 elems/block
__global__ __launch_bounds__(256) void scan1i_kernel(
    int* __restrict__ arr, int* __restrict__ bsum, int L) {
  __shared__ int tot[256];
  int t = threadIdx.x;
  int base = blockIdx.x * 4096 + t * 16;
  int v[16];
  int s = 0;
  #pragma unroll
  for (int q = 0; q < 16; ++q) {
    v[q] = (base + q < L) ? arr[base + q] : 0;
    s += v[q];
  }
  tot[t] = s;
  __syncthreads();
  for (int off = 1; off < 256; off <<= 1) {
    int y = (t >= off) ? tot[t - off] : 0;
    __syncthreads();
    tot[t] += y;
    __syncthreads();
  }
  int p = tot[t] - s;  // exclusive within block
  if (t == 255) bsum[blockIdx.x] = tot[255];
  #pragma unroll
  for (int q = 0; q < 16; ++q) {
    if (base + q < L) arr[base + q] = p;
    p += v[q];
  }
}

__global__ __launch_bounds__(256) void scan2_kernel(
    int* __restrict__ bsum, int nb) {
  __shared__ int buf[256];
  int t = threadIdx.x;
  int v = (t < nb) ? bsum[t] : 0;
  buf[t] = v;
  __syncthreads();
  for (int off = 1; off < 256; off <<= 1) {
    int y = (t >= off) ? buf[t - off] : 0;
    __syncthreads();
    buf[t] += y;
    __syncthreads();
  }
  if (t < nb) bsum[t] = buf[t] - v;  // exclusive
}

__global__ __launch_bounds__(256) void scan3_kernel(
    int* __restrict__ arr, const int* __restrict__ bsum, int L) {
  int i = blockIdx.x * 256 + threadIdx.x;
  if (i < L) arr[i] += bsum[i >> 12];
}

// ---------------- A3: bucketize edges -> bdw[pos] = {w(32) | l(8) | src(20)}
// 1024-thread blocks, EBLK=2048 -> only 2 serial chain iters per thread
__global__ __launch_bounds__(1024) void a3_bucketize_kernel(
    const int* __restrict__ src, const int* __restrict__ dst,
    const float* __restrict__ w, const int* __restrict__ gtable,
    unsigned long long* __restrict__ bdw, int E, int NBA) {
  __shared__ unsigned int bh[392];
  int bid = blockIdx.x;
  int tid = threadIdx.x;
  for (int k = tid; k < 392; k += 1024) bh[k] = 0u;
  __syncthreads();
  int e0 = bid * EBLK;
  #pragma unroll
  for (int it = 0; it < EBLK / 1024; ++it) {
    int e = e0 + it * 1024 + tid;
    if (e < E) {
      int d = dst[e];
      int k = d >> 8;
      unsigned int l = (unsigned int)(d & 255);
      unsigned int r = atomicAdd(&bh[k], 1u);
      int pos = gtable[k * NBA + bid] + (int)r;
      unsigned int lo = (unsigned int)src[e] | (l << 20);
      unsigned long long v = ((unsigned long long)__float_as_uint(w[e]) << 32)
                           | (unsigned long long)lo;
      bdw[pos] = v;
    }
  }
}

// ---------------- B12: per-bucket degree+rowptr+dinv, then CSR scatter
// pass2 re-reads the bucket's bdw L2-hot; edges carry {src, w*dinv[d]}
__global__ __launch_bounds__(1024) void b12_kernel(
    const unsigned long long* __restrict__ bdw,
    const int* __restrict__ gtable, int* __restrict__ rowptr,
    float* __restrict__ dinv, int2* __restrict__ edges,
    int E, int NBA, int NB, int N) {
  __shared__ unsigned int lcnt[256];
  __shared__ unsigned int lwfx[256];
  __shared__ int sc[256];
  __shared__ int lrp[256];
  __shared__ float ldv[256];
  int k = blockIdx.x;
  int t = threadIdx.x;
  if (t < 256) { lcnt[t] = 0u; lwfx[t] = 0u; }
  __syncthreads();
  int base = gtable[k * NBA];
  int end  = (k + 1 < NB) ? gtable[(k + 1) * NBA] : E;
  // pass 1: count + fixed-point weighted degree
  for (int i = base + t; i < end; i += 1024) {
    unsigned long long v = bdw[i];
    unsigned int lo = (unsigned int)v;
    unsigned int l = (lo >> 20) & 0xFFu;
    float wv = __uint_as_float((unsigned int)(v >> 32));
    atomicAdd(&lcnt[l], 1u);
    atomicAdd(&lwfx[l], (unsigned int)(wv * WFX));
  }
  __syncthreads();
  int c = 0;
  if (t < 256) { c = (int)lcnt[t]; sc[t] = c; }
  __syncthreads();
  for (int off = 1; off < 256; off <<= 1) {
    int y = (t >= off && t < 256) ? sc[t - off] : 0;
    __syncthreads();
    if (t < 256) sc[t] += y;
    __syncthreads();
  }
  if (t < 256) {
    int excl = sc[t] - c;
    int rp = base + excl;
    lrp[t] = rp;
    float di = rsqrtf(1.0f + (float)lwfx[t] * WFXI);
    ldv[t] = di;
    int node = (k << 8) + t;
    if (node < N) {
      rowptr[node] = rp;
      dinv[node] = di;
    }
    lcnt[t] = 0u;   // reset for rank pass
  }
  if (k == 0 && t == 0) rowptr[N] = E;
  __syncthreads();
  // pass 2: rank + write CSR edges {src, w*dinv[d]} (bdw L2-hot)
  for (int i = base + t; i < end; i += 1024) {
    unsigned long long v = bdw[i];
    unsigned int lo = (unsigned int)v;
    int s = (int)(lo & 0xFFFFFu);
    unsigned int l = (lo >> 20) & 0xFFu;
    float wv = __uint_as_float((unsigned int)(v >> 32));
    unsigned int r = atomicAdd(&lcnt[l], 1u);
    int pos = lrp[l] + (int)r;
    float wd = wv * ldv[l];
    edges[pos] = make_int2(s, __float_as_int(wd));
  }
}

// ---------------- MFMA GEMM2: H2h[N,64] fp16 = A1b[N,128] bf16 @ W2
__global__ __launch_bounds__(256) void gemm2_kernel(
    const unsigned short* __restrict__ A1b, const unsigned short* __restrict__ WT2,
    unsigned short* __restrict__ H2h, int N) {
  __shared__ __align__(16) short XS[64 * 40];   // 64 rows x 32 k
  __shared__ __align__(16) short WTS[64 * 40];  // 64 cols x 32 k
  int tid = threadIdx.x;
  int row0 = blockIdx.x * 64;
  int wave = tid >> 6, lane = tid & 63;
  int lr = lane & 15, lq = lane >> 4;
  f32x4 acc[4];
  #pragma unroll
  for (int c = 0; c < 4; ++c) acc[c] = (f32x4)(0.f);

  for (int k0 = 0; k0 < FH; k0 += 32) {
    {  // stage XS: row=t>>2, o=(t&3)*8 (A1b already bf16)
      int row = tid >> 2, o = (tid & 3) * 8;
      int gr = row0 + row;
      uint4 v = make_uint4(0u, 0u, 0u, 0u);
      if (gr < N) v = *(const uint4*)(A1b + (size_t)gr * FH + k0 + o);
      *(uint4*)(&XS[row * 40 + o]) = v;
    }
    {  // stage WTS: j=t>>2, o=(t&3)*8
      int j = tid >> 2, o = (tid & 3) * 8;
      uint4 v = *(const uint4*)(WT2 + (size_t)j * FH + k0 + o);
      *(uint4*)(&WTS[j * 40 + o]) = v;
    }
    __syncthreads();
    s16x8 af = *(const s16x8*)(&XS[(wave * 16 + lr) * 40 + lq * 8]);
    #pragma unroll
    for (int c = 0; c < 4; ++c) {
      s16x8 bf = *(const s16x8*)(&WTS[(c * 16 + lr) * 40 + lq * 8]);
      acc[c] = __builtin_amdgcn_mfma_f32_16x16x32_bf16(af, bf, acc[c], 0, 0, 0);
    }
    __syncthreads();
  }
  int orow = row0 + wave * 16 + lq * 4;
  #pragma unroll
  for (int c = 0; c < 4; ++c) {
    #pragma unroll
    for (int r = 0; r < 4; ++r) {
      int gr = orow + r;
      if (gr < N)
        H2h[(size_t)gr * FO + c * 16 + lr] = (unsigned short)f2h(acc[c][r]);
    }
  }
}

// ---------------- agg1: a1b = relu(A @ h1 + b1), 128 fp8 feats gathered
// quarter-wave per row: 16 lanes x 8B; 4 edges/wave x3 unroll = 12 in flight
// edge.y = w*dinv[d]; multiply dinv[src] at gather time
__global__ __launch_bounds__(256) void agg1_kernel(
    const unsigned char* __restrict__ H1q, const int2* __restrict__ edges,
    const int* __restrict__ rowptr, const float* __restrict__ dinv,
    const float* __restrict__ b1, unsigned short* __restrict__ A1b, int N) {
  int wid = (blockIdx.x * 256 + threadIdx.x) >> 6;
  int lane = threadIdx.x & 63;
  if (wid >= N) return;
  int p0 = rowptr[wid], p1 = rowptr[wid + 1];
  int grp = lane >> 4, li = lane & 15;      // li covers feats li*8..+7
  const size_t rowoff = (size_t)li * 8;     // bytes (fp8)
  float a0[8], a1v[8], a2v[8];
  #pragma unroll
  for (int j = 0; j < 8; ++j) { a0[j] = 0.f; a1v[j] = 0.f; a2v[j] = 0.f; }

  int p = p0;
  for (; p + 12 <= p1; p += 12) {
    int2 e0 = edges[p + grp];
    int2 e1 = edges[p + 4 + grp];
    int2 e2 = edges[p + 8 + grp];
    uint2 h0 = *(const uint2*)(H1q + (size_t)e0.x * FH + rowoff);
    uint2 h1 = *(const uint2*)(H1q + (size_t)e1.x * FH + rowoff);
    uint2 h2 = *(const uint2*)(H1q + (size_t)e2.x * FH + rowoff);
    float n0 = __int_as_float(e0.y) * dinv[e0.x];
    float n1 = __int_as_float(e1.y) * dinv[e1.x];
    float n2 = __int_as_float(e2.y) * dinv[e2.x];
    float f0[8], f1[8], f2[8];
    cvt8q(h0, f0); cvt8q(h1, f1); cvt8q(h2, f2);
    #pragma unroll
    for (int j = 0; j < 8; ++j) {
      a0[j] += n0 * f0[j];
      a1v[j] += n1 * f1[j];
      a2v[j] += n2 * f2[j];
    }
  }
  for (; p + 4 <= p1; p += 4) {
    int2 e0 = edges[p + grp];
    uint2 h0 = *(const uint2*)(H1q + (size_t)e0.x * FH + rowoff);
    float n0 = __int_as_float(e0.y) * dinv[e0.x];
    float f0[8];
    cvt8q(h0, f0);
    #pragma unroll
    for (int j = 0; j < 8; ++j) a0[j] += n0 * f0[j];
  }
  if (p < p1) {  // 1..3 leftover edges: masked
    int q = p + grp;
    int qi = (q < p1) ? q : p;
    int2 e0 = edges[qi];
    float n0 = (q < p1) ? __int_as_float(e0.y) * dinv[e0.x] : 0.f;
    uint2 h0 = *(const uint2*)(H1q + (size_t)e0.x * FH + rowoff);
    float f0[8];
    cvt8q(h0, f0);
    #pragma unroll
    for (int j = 0; j < 8; ++j) a0[j] += n0 * f0[j];
  }
  float s[8];
  #pragma unroll
  for (int j = 0; j < 8; ++j) {
    s[j] = (a0[j] + a1v[j]) + a2v[j];
    s[j] += __shfl_xor(s[j], 16);
    s[j] += __shfl_xor(s[j], 32);
  }
  if (lane < 16) {
    float di = dinv[wid], sn = di * di;
    uint2 hs = *(const uint2*)(H1q + (size_t)wid * FH + rowoff);
    float fs[8];
    cvt8q(hs, fs);
    #pragma unroll
    for (int j = 0; j < 8; ++j) s[j] += sn * fs[j];
    float4 bv0 = *(const float4*)(b1 + li * 8);
    float4 bv1 = *(const float4*)(b1 + li * 8 + 4);
    s[0] = fmaxf(s[0] + bv0.x, 0.f); s[1] = fmaxf(s[1] + bv0.y, 0.f);
    s[2] = fmaxf(s[2] + bv0.z, 0.f); s[3] = fmaxf(s[3] + bv0.w, 0.f);
    s[4] = fmaxf(s[4] + bv1.x, 0.f); s[5] = fmaxf(s[5] + bv1.y, 0.f);
    s[6] = fmaxf(s[6] + bv1.z, 0.f); s[7] = fmaxf(s[7] + bv1.w, 0.f);
    uint4 pk;
    pk.x = f2bf(s[0]) | (f2bf(s[1]) << 16);
    pk.y = f2bf(s[2]) | (f2bf(s[3]) << 16);
    pk.z = f2bf(s[4]) | (f2bf(s[5]) << 16);
    pk.w = f2bf(s[6]) | (f2bf(s[7]) << 16);
    *(uint4*)(A1b + (size_t)wid * FH + li * 8) = pk;
  }
}

// ---------------- agg2: out = A @ h2 + b2, 64 fp16 feats
// eighth-wave per row: 8 lanes x 16B; 8 edges/wave x2 unroll = 16 in flight
__global__ __launch_bounds__(256) void agg2_kernel(
    const unsigned short* __restrict__ H2h, const int2* __restrict__ edges,
    const int* __restrict__ rowptr, const float* __restrict__ dinv,
    const float* __restrict__ b2, float* __restrict__ OUT, int N) {
  int wid = (blockIdx.x * 256 + threadIdx.x) >> 6;
  int lane = threadIdx.x & 63;
  if (wid >= N) return;
  int p0 = rowptr[wid], p1 = rowptr[wid + 1];
  int grp = lane >> 3, li = lane & 7;       // li covers feats li*8..+7
  const size_t rowoff = (size_t)li * 8;
  float a0[8], a1v[8];
  #pragma unroll
  for (int j = 0; j < 8; ++j) { a0[j] = 0.f; a1v[j] = 0.f; }

  int p = p0;
  for (; p + 16 <= p1; p += 16) {
    int2 e0 = edges[p + grp];
    int2 e1 = edges[p + 8 + grp];
    uint4 h0 = *(const uint4*)(H2h + (size_t)e0.x * FO + rowoff);
    uint4 h1 = *(const uint4*)(H2h + (size_t)e1.x * FO + rowoff);
    float n0 = __int_as_float(e0.y) * dinv[e0.x];
    float n1 = __int_as_float(e1.y) * dinv[e1.x];
    float f0[8], f1[8];
    cvt8(h0, f0); cvt8(h1, f1);
    #pragma unroll
    for (int j = 0; j < 8; ++j) {
      a0[j] += n0 * f0[j];
      a1v[j] += n1 * f1[j];
    }
  }
  for (; p + 8 <= p1; p += 8) {
    int2 e0 = edges[p + grp];
    uint4 h0 = *(const uint4*)(H2h + (size_t)e0.x * FO + rowoff);
    float n0 = __int_as_float(e0.y) * dinv[e0.x];
    float f0[8];
    cvt8(h0, f0);
    #pragma unroll
    for (int j = 0; j < 8; ++j) a0[j] += n0 * f0[j];
  }
  if (p < p1) {  // 1..7 leftover edges: masked
    int q = p + grp;
    int qi = (q < p1) ? q : p;
    int2 e0 = edges[qi];
    float n0 = (q < p1) ? __int_as_float(e0.y) * dinv[e0.x] : 0.f;
    uint4 h0 = *(const uint4*)(H2h + (size_t)e0.x * FO + rowoff);
    float f0[8];
    cvt8(h0, f0);
    #pragma unroll
    for (int j = 0; j < 8; ++j) a0[j] += n0 * f0[j];
  }
  float s[8];
  #pragma unroll
  for (int j = 0; j < 8; ++j) {
    s[j] = a0[j] + a1v[j];
    s[j] += __shfl_xor(s[j], 8);
    s[j] += __shfl_xor(s[j], 16);
    s[j] += __shfl_xor(s[j], 32);
  }
  if (lane < 8) {
    float di = dinv[wid], sn = di * di;
    uint4 hs = *(const uint4*)(H2h + (size_t)wid * FO + rowoff);
    float fs[8];
    cvt8(hs, fs);
    #pragma unroll
    for (int j = 0; j < 8; ++j) s[j] += sn * fs[j];
    float4 bv0 = *(const float4*)(b2 + li * 8);
    float4 bv1 = *(const float4*)(b2 + li * 8 + 4);
    float4 o0 = make_float4(s[0] + bv0.x, s[1] + bv0.y, s[2] + bv0.z, s[3] + bv0.w);
    float4 o1 = make_float4(s[4] + bv1.x, s[5] + bv1.y, s[6] + bv1.z, s[7] + bv1.w);
    *(float4*)(OUT + (size_t)wid * FO + li * 8) = o0;
    *(float4*)(OUT + (size_t)wid * FO + li * 8 + 4) = o1;
  }
}

extern "C" void kernel_launch(void* const* d_in, const int* in_sizes, int n_in,
                              void* d_out, int out_size, void* d_ws, size_t ws_size,
                              hipStream_t stream) {
  const float* x  = (const float*)d_in[0];
  const int*   ei = (const int*)d_in[1];
  const float* ew = (const float*)d_in[2];
  const float* W1 = (const float*)d_in[3];
  const float* b1 = (const float*)d_in[4];
  const float* W2 = (const float*)d_in[5];
  const float* b2 = (const float*)d_in[6];
  float* out = (float*)d_out;

  const int N = in_sizes[0] / FIN;        // 100000
  const int E = in_sizes[2];              // 3200000
  const int* src = ei;
  const int* dst = ei + E;
  const int NBG = (N + 63) / 64;          // gemm1 tiles (1563)
  const int NBA = (E + EBLK - 1) / EBLK;  // A-phase blocks (1563)
  const int NB  = (N + 255) / 256;        // buckets (391)
  const int L   = NB * NBA;               // gtable length (~611K)
  const int nsb = (L + 4095) / 4096;      // scan blocks (150, <=256)

  // workspace layout (16B-aligned slices), ~106MB total
  char* ws = (char*)d_ws;
  size_t off = 0;
  unsigned char*  h1q = (unsigned char*)(ws + off);  off += (size_t)N * FH;      // fp8 h1
  unsigned short* h2h = (unsigned short*)(ws + off); off += (size_t)N * FO * 2;  // fp16 h2
  unsigned short* a1b = (unsigned short*)(ws + off); off += (size_t)N * FH * 2;  // bf16 a1
  int2*  edges  = (int2*) (ws + off); off += (size_t)E * 8;
  unsigned long long* bdw = (unsigned long long*)(ws + off); off += (size_t)E * 8;
  int*   gtable = (int*)  (ws + off); off += (((size_t)L * 4) + 15) & ~(size_t)15;
  int*   rowptr = (int*)  (ws + off); off += (((size_t)(N + 1) * 4) + 15) & ~(size_t)15;
  float* dinv   = (float*)(ws + off); off += (size_t)N * 4;
  int*   bsum   = (int*)  (ws + off); off += 1024;
  unsigned short* WT1 = (unsigned short*)(ws + off); off += (size_t)FH * FIN * 2;  // bf16 W1^T
  unsigned short* WT2 = (unsigned short*)(ws + off); off += (size_t)FO * FH * 2;   // bf16 W2^T

  // weight transpose + bf16 cvt (tiny, off critical path)
  prep_w_kernel<<<(FIN * FH + FH * FO + 255) / 256, 256, 0, stream>>>(W1, W2, WT1, WT2);
  // CSR build (LDS-atomic bucketed) + MFMA gemm1 fused
  a1hist_gemm1_kernel<<<NBA + NBG, 256, 0, stream>>>(dst, gtable, E, NBA, NB,
                                                     x, WT1, h1q, N, NBG);
  scan1i_kernel<<<nsb, 256, 0, stream>>>(gtable, bsum, L);
  scan2_kernel<<<1, 256, 0, stream>>>(bsum, nsb);
  scan3_kernel<<<(L + 255) / 256, 256, 0, stream>>>(gtable, bsum, L);
  a3_bucketize_kernel<<<NBA, 1024, 0, stream>>>(src, dst, ew, gtable, bdw, E, NBA);
  b12_kernel<<<NB, 1024, 0, stream>>>(bdw, gtable, rowptr, dinv, edges,
                                      E, NBA, NB, N);
  // layers
  agg1_kernel<<<(N * 64 + 255) / 256, 256, 0, stream>>>(h1q, edges, rowptr,
                                                        dinv, b1, a1b, N);
  gemm2_kernel<<<(N + 63) / 64, 256, 0, stream>>>(a1b, WT2, h2h, N);
  agg2_kernel<<<(N * 64 + 255) / 256, 256, 0, stream>>>(h2h, edges, rowptr,
                                                        dinv, b2, out, N);
}

// Round 18
// 305.067 us; speedup vs baseline: 1.3135x; 1.0112x over previous
//
#include <hip/hip_runtime.h>
#include <hip/hip_bf16.h>
#include <hip/hip_fp16.h>

// GCN 2-layer encoder: N=100000 nodes, E=3.2M edges, Fin=256, Fh=128, Fo=64.
//   h1 = x@W1 ; a1 = relu(A@h1 + b1) ; h2 = a1@W2 ; out = A@h2 + b2
//
// R18: R17's dinv-at-gather cost agg1 65->86us (extra random load+mul on
// the latency-critical gather loop) while the build fusion saved ~50us.
// Fix: keep b12 (edges written with w*dinv[d]) and add a ~12us streaming
// fixup pass AFTER b12 (dinv globally complete): edges.y *= dinv[edges.x].
// agg1/agg2 revert to clean full-norm edges (R16 inner loops).
// Rest: fp8 h1, MFMA gemms, LDS-atomic bucketed CSR, EBLK=2048 a3.

#define FIN 256
#define FH  128
#define FO  64

#define EBLK 2048                     // edges per A-phase block
#define WFX  33554432.0f              // 2^25 fixed-point degree scale
#define WFXI (1.0f / 33554432.0f)

typedef short s16x8 __attribute__((ext_vector_type(8)));
typedef float f32x4 __attribute__((ext_vector_type(4)));
typedef float f32x2 __attribute__((ext_vector_type(2)));

__device__ __forceinline__ unsigned int f2h(float f) {
  union { _Float16 h; unsigned short s; } c; c.h = (_Float16)f;  // RNE cvt
  return (unsigned int)c.s;
}
__device__ __forceinline__ unsigned int f2bf(float f) {
  union { float f; unsigned int i; } c; c.f = f;
  unsigned int i = c.i;
  return (i + 0x7FFFu + ((i >> 16) & 1u)) >> 16;  // RNE
}
// unpack uint4 of 8 fp16 -> 8 f32 via packed cvt (no shifts)
__device__ __forceinline__ void cvt8(const uint4& v, float* f) {
  const __half2* hp = (const __half2*)&v;
  #pragma unroll
  for (int j = 0; j < 4; ++j) {
    float2 t = __half22float2(hp[j]);
    f[2 * j] = t.x; f[2 * j + 1] = t.y;
  }
}
// unpack uint2 of 8 fp8(e4m3) -> 8 f32 via v_cvt_pk_f32_fp8
__device__ __forceinline__ void cvt8q(const uint2& v, float* f) {
  f32x2 t0 = __builtin_amdgcn_cvt_pk_f32_fp8((int)v.x, false);
  f32x2 t1 = __builtin_amdgcn_cvt_pk_f32_fp8((int)v.x, true);
  f32x2 t2 = __builtin_amdgcn_cvt_pk_f32_fp8((int)v.y, false);
  f32x2 t3 = __builtin_amdgcn_cvt_pk_f32_fp8((int)v.y, true);
  f[0] = t0[0]; f[1] = t0[1]; f[2] = t1[0]; f[3] = t1[1];
  f[4] = t2[0]; f[5] = t2[1]; f[6] = t3[0]; f[7] = t3[1];
}

// ---------------- prep: WT1[j][k]=bf16(W1[k][j]); WT2[j][k]=bf16(W2[k][j])
__global__ __launch_bounds__(256) void prep_w_kernel(
    const float* __restrict__ W1, const float* __restrict__ W2,
    unsigned short* __restrict__ WT1, unsigned short* __restrict__ WT2) {
  int i = blockIdx.x * 256 + threadIdx.x;
  if (i < FIN * FH) {
    int k = i >> 7, j = i & 127;
    WT1[j * FIN + k] = (unsigned short)f2bf(W1[i]);
  } else {
    int i2 = i - FIN * FH;
    if (i2 < FH * FO) {
      int k = i2 >> 6, j = i2 & 63;
      WT2[j * FH + k] = (unsigned short)f2bf(W2[i2]);
    }
  }
}

// ---------------- A1 hist (blocks [0,NBA)) + MFMA gemm1 (blocks [NBA,..))
// gemm1 writes h1 as fp8 e4m3
__global__ __launch_bounds__(256) void a1hist_gemm1_kernel(
    const int* __restrict__ dst, int* __restrict__ gtable, int E,
    int NBA, int NB,
    const float* __restrict__ X, const unsigned short* __restrict__ WT1,
    unsigned char* __restrict__ H1q, int N, int NBG) {
  __shared__ __align__(16) short XS[64 * 40];    // 64 rows x 32 k (bf16)
  __shared__ __align__(16) short WTS[128 * 40];  // 128 cols x 32 k (bf16)
  __shared__ unsigned int bh[392];
  int bid = blockIdx.x;
  int tid = threadIdx.x;
  if (bid < NBA) {
    // ---- bucket-histogram role
    for (int k = tid; k < NB; k += 256) bh[k] = 0u;
    __syncthreads();
    int e0 = bid * EBLK;
    #pragma unroll 4
    for (int it = 0; it < EBLK / 256; ++it) {
      int e = e0 + it * 256 + tid;
      if (e < E) atomicAdd(&bh[dst[e] >> 8], 1u);
    }
    __syncthreads();
    for (int k = tid; k < NB; k += 256)
      gtable[k * NBA + bid] = (int)bh[k];
    return;
  }
  int g = bid - NBA;
  if (g >= NBG) return;
  // ---- MFMA gemm1 role: H1q[64 rows,128 cols] fp8 = X @ W1 (bf16 MFMA)
  int row0 = g * 64;
  int wave = tid >> 6, lane = tid & 63;
  int lr = lane & 15, lq = lane >> 4;          // fragment row & k-octet
  f32x4 acc[8];
  #pragma unroll
  for (int c = 0; c < 8; ++c) acc[c] = (f32x4)(0.f);

  for (int k0 = 0; k0 < FIN; k0 += 32) {
    {  // stage XS: thread t -> row t>>2, koff (t&3)*8 ; f32 -> bf16
      int row = tid >> 2, koff = (tid & 3) * 8;
      int gr = row0 + row;
      float4 va = make_float4(0.f, 0.f, 0.f, 0.f), vb = va;
      if (gr < N) {
        va = *(const float4*)(X + (size_t)gr * FIN + k0 + koff);
        vb = *(const float4*)(X + (size_t)gr * FIN + k0 + koff + 4);
      }
      s16x8 hv;
      hv[0] = (short)f2bf(va.x); hv[1] = (short)f2bf(va.y);
      hv[2] = (short)f2bf(va.z); hv[3] = (short)f2bf(va.w);
      hv[4] = (short)f2bf(vb.x); hv[5] = (short)f2bf(vb.y);
      hv[6] = (short)f2bf(vb.z); hv[7] = (short)f2bf(vb.w);
      *(s16x8*)(&XS[row * 40 + koff]) = hv;
    }
    {  // stage WTS: thread t -> j t>>1, 16-half o (t&1)*16 (WT1 is bf16)
      int j = tid >> 1, o = (tid & 1) * 16;
      uint4 v0 = *(const uint4*)(WT1 + (size_t)j * FIN + k0 + o);
      uint4 v1 = *(const uint4*)(WT1 + (size_t)j * FIN + k0 + o + 8);
      *(uint4*)(&WTS[j * 40 + o]) = v0;
      *(uint4*)(&WTS[j * 40 + o + 8]) = v1;
    }
    __syncthreads();
    s16x8 af = *(const s16x8*)(&XS[(wave * 16 + lr) * 40 + lq * 8]);
    #pragma unroll
    for (int c = 0; c < 8; ++c) {
      s16x8 bf = *(const s16x8*)(&WTS[(c * 16 + lr) * 40 + lq * 8]);
      acc[c] = __builtin_amdgcn_mfma_f32_16x16x32_bf16(af, bf, acc[c], 0, 0, 0);
    }
    __syncthreads();
  }
  // epilogue: D row=(l>>4)*4+r (within wave's 16), col=c*16+(l&15); fp8 out
  int orow = row0 + wave * 16 + lq * 4;
  #pragma unroll
  for (int c = 0; c < 8; ++c) {
    #pragma unroll
    for (int r = 0; r < 4; ++r) {
      int gr = orow + r;
      if (gr < N) {
        int pk = __builtin_amdgcn_cvt_pk_fp8_f32(acc[c][r], acc[c][r], 0, false);
        H1q[(size_t)gr * FH + c * 16 + lr] = (unsigned char)(pk & 0xff);
      }
    }
  }
}

// ---------------- 3-phase exclusive scan, in-place, 4096 elems/block
__global__ __launch_bounds__(256) void scan1i_kernel(
    int* __restrict__ arr, int* __restrict__ bsum, int L) {
  __shared__ int tot[256];
  int t = threadIdx.x;
  int base = blockIdx.x * 4096 + t * 16;
  int v[16];
  int s = 0;
  #pragma unroll
  for (int q = 0; q < 16; ++q) {
    v[q] = (base + q < L) ? arr[base + q] : 0;
    s += v[q];
  }
  tot[t] = s;
  __syncthreads();
  for (int off = 1; off < 256; off <<= 1) {
    int y = (t >= off) ? tot[t - off] : 0;
    __syncthreads();
    tot[t] += y;
    __syncthreads();
  }
  int p = tot[t] - s;  // exclusive within block
  if (t == 255) bsum[blockIdx.x] = tot[255];
  #pragma unroll
  for (int q = 0; q < 16; ++q) {
    if (base + q < L) arr[base + q] = p;
    p += v[q];
  }
}

__global__ __launch_bounds__(256) void scan2_kernel(
    int* __restrict__ bsum, int nb) {
  __shared__ int buf[256];
  int t = threadIdx.x;
  int v = (t < nb) ? bsum[t] : 0;
  buf[t] = v;
  __syncthreads();
  for (int off = 1; off < 256; off <<= 1) {
    int y = (t >= off) ? buf[t - off] : 0;
    __syncthreads();
    buf[t] += y;
    __syncthreads();
  }
  if (t < nb) bsum[t] = buf[t] - v;  // exclusive
}

__global__ __launch_bounds__(256) void scan3_kernel(
    int* __restrict__ arr, const int* __restrict__ bsum, int L) {
  int i = blockIdx.x * 256 + threadIdx.x;
  if (i < L) arr[i] += bsum[i >> 12];
}

// ---------------- A3: bucketize edges -> bdw[pos] = {w(32) | l(8) | src(20)}
// 1024-thread blocks, EBLK=2048 -> only 2 serial chain iters per thread
__global__ __launch_bounds__(1024) void a3_bucketize_kernel(
    const int* __restrict__ src, const int* __restrict__ dst,
    const float* __restrict__ w, const int* __restrict__ gtable,
    unsigned long long* __restrict__ bdw, int E, int NBA) {
  __shared__ unsigned int bh[392];
  int bid = blockIdx.x;
  int tid = threadIdx.x;
  for (int k = tid; k < 392; k += 1024) bh[k] = 0u;
  __syncthreads();
  int e0 = bid * EBLK;
  #pragma unroll
  for (int it = 0; it < EBLK / 1024; ++it) {
    int e = e0 + it * 1024 + tid;
    if (e < E) {
      int d = dst[e];
      int k = d >> 8;
      unsigned int l = (unsigned int)(d & 255);
      unsigned int r = atomicAdd(&bh[k], 1u);
      int pos = gtable[k * NBA + bid] + (int)r;
      unsigned int lo = (unsigned int)src[e] | (l << 20);
      unsigned long long v = ((unsigned long long)__float_as_uint(w[e]) << 32)
                           | (unsigned long long)lo;
      bdw[pos] = v;
    }
  }
}

// ---------------- B12: per-bucket degree+rowptr+dinv, then CSR scatter
// pass2 re-reads the bucket's bdw L2-hot; edges carry {src, w*dinv[d]}
__global__ __launch_bounds__(1024) void b12_kernel(
    const unsigned long long* __restrict__ bdw,
    const int* __restrict__ gtable, int* __restrict__ rowptr,
    float* __restrict__ dinv, int2* __restrict__ edges,
    int E, int NBA, int NB, int N) {
  __shared__ unsigned int lcnt[256];
  __shared__ unsigned int lwfx[256];
  __shared__ int sc[256];
  __shared__ int lrp[256];
  __shared__ float ldv[256];
  int k = blockIdx.x;
  int t = threadIdx.x;
  if (t < 256) { lcnt[t] = 0u; lwfx[t] = 0u; }
  __syncthreads();
  int base = gtable[k * NBA];
  int end  = (k + 1 < NB) ? gtable[(k + 1) * NBA] : E;
  // pass 1: count + fixed-point weighted degree
  for (int i = base + t; i < end; i += 1024) {
    unsigned long long v = bdw[i];
    unsigned int lo = (unsigned int)v;
    unsigned int l = (lo >> 20) & 0xFFu;
    float wv = __uint_as_float((unsigned int)(v >> 32));
    atomicAdd(&lcnt[l], 1u);
    atomicAdd(&lwfx[l], (unsigned int)(wv * WFX));
  }
  __syncthreads();
  int c = 0;
  if (t < 256) { c = (int)lcnt[t]; sc[t] = c; }
  __syncthreads();
  for (int off = 1; off < 256; off <<= 1) {
    int y = (t >= off && t < 256) ? sc[t - off] : 0;
    __syncthreads();
    if (t < 256) sc[t] += y;
    __syncthreads();
  }
  if (t < 256) {
    int excl = sc[t] - c;
    int rp = base + excl;
    lrp[t] = rp;
    float di = rsqrtf(1.0f + (float)lwfx[t] * WFXI);
    ldv[t] = di;
    int node = (k << 8) + t;
    if (node < N) {
      rowptr[node] = rp;
      dinv[node] = di;
    }
    lcnt[t] = 0u;   // reset for rank pass
  }
  if (k == 0 && t == 0) rowptr[N] = E;
  __syncthreads();
  // pass 2: rank + write CSR edges {src, w*dinv[d]} (bdw L2-hot)
  for (int i = base + t; i < end; i += 1024) {
    unsigned long long v = bdw[i];
    unsigned int lo = (unsigned int)v;
    int s = (int)(lo & 0xFFFFFu);
    unsigned int l = (lo >> 20) & 0xFFu;
    float wv = __uint_as_float((unsigned int)(v >> 32));
    unsigned int r = atomicAdd(&lcnt[l], 1u);
    int pos = lrp[l] + (int)r;
    float wd = wv * ldv[l];
    edges[pos] = make_int2(s, __float_as_int(wd));
  }
}

// ---------------- fixup: edges.y *= dinv[edges.x]  (dinv complete after b12)
__global__ __launch_bounds__(256) void fixup_kernel(
    int2* __restrict__ edges, const float* __restrict__ dinv, int E) {
  int i = blockIdx.x * 256 + threadIdx.x;
  if (i < E) {
    int2 e = edges[i];
    e.y = __float_as_int(__int_as_float(e.y) * dinv[e.x]);
    edges[i] = e;
  }
}

// ---------------- MFMA GEMM2: H2h[N,64] fp16 = A1b[N,128] bf16 @ W2
__global__ __launch_bounds__(256) void gemm2_kernel(
    const unsigned short* __restrict__ A1b, const unsigned short* __restrict__ WT2,
    unsigned short* __restrict__ H2h, int N) {
  __shared__ __align__(16) short XS[64 * 40];   // 64 rows x 32 k
  __shared__ __align__(16) short WTS[64 * 40];  // 64 cols x 32 k
  int tid = threadIdx.x;
  int row0 = blockIdx.x * 64;
  int wave = tid >> 6, lane = tid & 63;
  int lr = lane & 15, lq = lane >> 4;
  f32x4 acc[4];
  #pragma unroll
  for (int c = 0; c < 4; ++c) acc[c] = (f32x4)(0.f);

  for (int k0 = 0; k0 < FH; k0 += 32) {
    {  // stage XS: row=t>>2, o=(t&3)*8 (A1b already bf16)
      int row = tid >> 2, o = (tid & 3) * 8;
      int gr = row0 + row;
      uint4 v = make_uint4(0u, 0u, 0u, 0u);
      if (gr < N) v = *(const uint4*)(A1b + (size_t)gr * FH + k0 + o);
      *(uint4*)(&XS[row * 40 + o]) = v;
    }
    {  // stage WTS: j=t>>2, o=(t&3)*8
      int j = tid >> 2, o = (tid & 3) * 8;
      uint4 v = *(const uint4*)(WT2 + (size_t)j * FH + k0 + o);
      *(uint4*)(&WTS[j * 40 + o]) = v;
    }
    __syncthreads();
    s16x8 af = *(const s16x8*)(&XS[(wave * 16 + lr) * 40 + lq * 8]);
    #pragma unroll
    for (int c = 0; c < 4; ++c) {
      s16x8 bf = *(const s16x8*)(&WTS[(c * 16 + lr) * 40 + lq * 8]);
      acc[c] = __builtin_amdgcn_mfma_f32_16x16x32_bf16(af, bf, acc[c], 0, 0, 0);
    }
    __syncthreads();
  }
  int orow = row0 + wave * 16 + lq * 4;
  #pragma unroll
  for (int c = 0; c < 4; ++c) {
    #pragma unroll
    for (int r = 0; r < 4; ++r) {
      int gr = orow + r;
      if (gr < N)
        H2h[(size_t)gr * FO + c * 16 + lr] = (unsigned short)f2h(acc[c][r]);
    }
  }
}

// ---------------- agg1: a1b = relu(A @ h1 + b1), 128 fp8 feats gathered
// quarter-wave per row: 16 lanes x 8B; 4 edges/wave x3 unroll = 12 in flight
__global__ __launch_bounds__(256) void agg1_kernel(
    const unsigned char* __restrict__ H1q, const int2* __restrict__ edges,
    const int* __restrict__ rowptr, const float* __restrict__ dinv,
    const float* __restrict__ b1, unsigned short* __restrict__ A1b, int N) {
  int wid = (blockIdx.x * 256 + threadIdx.x) >> 6;
  int lane = threadIdx.x & 63;
  if (wid >= N) return;
  int p0 = rowptr[wid], p1 = rowptr[wid + 1];
  int grp = lane >> 4, li = lane & 15;      // li covers feats li*8..+7
  const size_t rowoff = (size_t)li * 8;     // bytes (fp8)
  float a0[8], a1v[8], a2v[8];
  #pragma unroll
  for (int j = 0; j < 8; ++j) { a0[j] = 0.f; a1v[j] = 0.f; a2v[j] = 0.f; }

  int p = p0;
  for (; p + 12 <= p1; p += 12) {
    int2 e0 = edges[p + grp];
    int2 e1 = edges[p + 4 + grp];
    int2 e2 = edges[p + 8 + grp];
    uint2 h0 = *(const uint2*)(H1q + (size_t)e0.x * FH + rowoff);
    uint2 h1 = *(const uint2*)(H1q + (size_t)e1.x * FH + rowoff);
    uint2 h2 = *(const uint2*)(H1q + (size_t)e2.x * FH + rowoff);
    float n0 = __int_as_float(e0.y), n1 = __int_as_float(e1.y);
    float n2 = __int_as_float(e2.y);
    float f0[8], f1[8], f2[8];
    cvt8q(h0, f0); cvt8q(h1, f1); cvt8q(h2, f2);
    #pragma unroll
    for (int j = 0; j < 8; ++j) {
      a0[j] += n0 * f0[j];
      a1v[j] += n1 * f1[j];
      a2v[j] += n2 * f2[j];
    }
  }
  for (; p + 4 <= p1; p += 4) {
    int2 e0 = edges[p + grp];
    uint2 h0 = *(const uint2*)(H1q + (size_t)e0.x * FH + rowoff);
    float n0 = __int_as_float(e0.y);
    float f0[8];
    cvt8q(h0, f0);
    #pragma unroll
    for (int j = 0; j < 8; ++j) a0[j] += n0 * f0[j];
  }
  if (p < p1) {  // 1..3 leftover edges: masked
    int q = p + grp;
    int qi = (q < p1) ? q : p;
    int2 e0 = edges[qi];
    float n0 = (q < p1) ? __int_as_float(e0.y) : 0.f;
    uint2 h0 = *(const uint2*)(H1q + (size_t)e0.x * FH + rowoff);
    float f0[8];
    cvt8q(h0, f0);
    #pragma unroll
    for (int j = 0; j < 8; ++j) a0[j] += n0 * f0[j];
  }
  float s[8];
  #pragma unroll
  for (int j = 0; j < 8; ++j) {
    s[j] = (a0[j] + a1v[j]) + a2v[j];
    s[j] += __shfl_xor(s[j], 16);
    s[j] += __shfl_xor(s[j], 32);
  }
  if (lane < 16) {
    float di = dinv[wid], sn = di * di;
    uint2 hs = *(const uint2*)(H1q + (size_t)wid * FH + rowoff);
    float fs[8];
    cvt8q(hs, fs);
    #pragma unroll
    for (int j = 0; j < 8; ++j) s[j] += sn * fs[j];
    float4 bv0 = *(const float4*)(b1 + li * 8);
    float4 bv1 = *(const float4*)(b1 + li * 8 + 4);
    s[0] = fmaxf(s[0] + bv0.x, 0.f); s[1] = fmaxf(s[1] + bv0.y, 0.f);
    s[2] = fmaxf(s[2] + bv0.z, 0.f); s[3] = fmaxf(s[3] + bv0.w, 0.f);
    s[4] = fmaxf(s[4] + bv1.x, 0.f); s[5] = fmaxf(s[5] + bv1.y, 0.f);
    s[6] = fmaxf(s[6] + bv1.z, 0.f); s[7] = fmaxf(s[7] + bv1.w, 0.f);
    uint4 pk;
    pk.x = f2bf(s[0]) | (f2bf(s[1]) << 16);
    pk.y = f2bf(s[2]) | (f2bf(s[3]) << 16);
    pk.z = f2bf(s[4]) | (f2bf(s[5]) << 16);
    pk.w = f2bf(s[6]) | (f2bf(s[7]) << 16);
    *(uint4*)(A1b + (size_t)wid * FH + li * 8) = pk;
  }
}

// ---------------- agg2: out = A @ h2 + b2, 64 fp16 feats
// eighth-wave per row: 8 lanes x 16B; 8 edges/wave x2 unroll = 16 in flight
__global__ __launch_bounds__(256) void agg2_kernel(
    const unsigned short* __restrict__ H2h, const int2* __restrict__ edges,
    const int* __restrict__ rowptr, const float* __restrict__ dinv,
    const float* __restrict__ b2, float* __restrict__ OUT, int N) {
  int wid = (blockIdx.x * 256 + threadIdx.x) >> 6;
  int lane = threadIdx.x & 63;
  if (wid >= N) return;
  int p0 = rowptr[wid], p1 = rowptr[wid + 1];
  int grp = lane >> 3, li = lane & 7;       // li covers feats li*8..+7
  const size_t rowoff = (size_t)li * 8;
  float a0[8], a1v[8];
  #pragma unroll
  for (int j = 0; j < 8; ++j) { a0[j] = 0.f; a1v[j] = 0.f; }

  int p = p0;
  for (; p + 16 <= p1; p += 16) {
    int2 e0 = edges[p + grp];
    int2 e1 = edges[p + 8 + grp];
    uint4 h0 = *(const uint4*)(H2h + (size_t)e0.x * FO + rowoff);
    uint4 h1 = *(const uint4*)(H2h + (size_t)e1.x * FO + rowoff);
    float n0 = __int_as_float(e0.y), n1 = __int_as_float(e1.y);
    float f0[8], f1[8];
    cvt8(h0, f0); cvt8(h1, f1);
    #pragma unroll
    for (int j = 0; j < 8; ++j) {
      a0[j] += n0 * f0[j];
      a1v[j] += n1 * f1[j];
    }
  }
  for (; p + 8 <= p1; p += 8) {
    int2 e0 = edges[p + grp];
    uint4 h0 = *(const uint4*)(H2h + (size_t)e0.x * FO + rowoff);
    float n0 = __int_as_float(e0.y);
    float f0[8];
    cvt8(h0, f0);
    #pragma unroll
    for (int j = 0; j < 8; ++j) a0[j] += n0 * f0[j];
  }
  if (p < p1) {  // 1..7 leftover edges: masked
    int q = p + grp;
    int qi = (q < p1) ? q : p;
    int2 e0 = edges[qi];
    float n0 = (q < p1) ? __int_as_float(e0.y) : 0.f;
    uint4 h0 = *(const uint4*)(H2h + (size_t)e0.x * FO + rowoff);
    float f0[8];
    cvt8(h0, f0);
    #pragma unroll
    for (int j = 0; j < 8; ++j) a0[j] += n0 * f0[j];
  }
  float s[8];
  #pragma unroll
  for (int j = 0; j < 8; ++j) {
    s[j] = a0[j] + a1v[j];
    s[j] += __shfl_xor(s[j], 8);
    s[j] += __shfl_xor(s[j], 16);
    s[j] += __shfl_xor(s[j], 32);
  }
  if (lane < 8) {
    float di = dinv[wid], sn = di * di;
    uint4 hs = *(const uint4*)(H2h + (size_t)wid * FO + rowoff);
    float fs[8];
    cvt8(hs, fs);
    #pragma unroll
    for (int j = 0; j < 8; ++j) s[j] += sn * fs[j];
    float4 bv0 = *(const float4*)(b2 + li * 8);
    float4 bv1 = *(const float4*)(b2 + li * 8 + 4);
    float4 o0 = make_float4(s[0] + bv0.x, s[1] + bv0.y, s[2] + bv0.z, s[3] + bv0.w);
    float4 o1 = make_float4(s[4] + bv1.x, s[5] + bv1.y, s[6] + bv1.z, s[7] + bv1.w);
    *(float4*)(OUT + (size_t)wid * FO + li * 8) = o0;
    *(float4*)(OUT + (size_t)wid * FO + li * 8 + 4) = o1;
  }
}

extern "C" void kernel_launch(void* const* d_in, const int* in_sizes, int n_in,
                              void* d_out, int out_size, void* d_ws, size_t ws_size,
                              hipStream_t stream) {
  const float* x  = (const float*)d_in[0];
  const int*   ei = (const int*)d_in[1];
  const float* ew = (const float*)d_in[2];
  const float* W1 = (const float*)d_in[3];
  const float* b1 = (const float*)d_in[4];
  const float* W2 = (const float*)d_in[5];
  const float* b2 = (const float*)d_in[6];
  float* out = (float*)d_out;

  const int N = in_sizes[0] / FIN;        // 100000
  const int E = in_sizes[2];              // 3200000
  const int* src = ei;
  const int* dst = ei + E;
  const int NBG = (N + 63) / 64;          // gemm1 tiles (1563)
  const int NBA = (E + EBLK - 1) / EBLK;  // A-phase blocks (1563)
  const int NB  = (N + 255) / 256;        // buckets (391)
  const int L   = NB * NBA;               // gtable length (~611K)
  const int nsb = (L + 4095) / 4096;      // scan blocks (150, <=256)

  // workspace layout (16B-aligned slices), ~106MB total
  char* ws = (char*)d_ws;
  size_t off = 0;
  unsigned char*  h1q = (unsigned char*)(ws + off);  off += (size_t)N * FH;      // fp8 h1
  unsigned short* h2h = (unsigned short*)(ws + off); off += (size_t)N * FO * 2;  // fp16 h2
  unsigned short* a1b = (unsigned short*)(ws + off); off += (size_t)N * FH * 2;  // bf16 a1
  int2*  edges  = (int2*) (ws + off); off += (size_t)E * 8;
  unsigned long long* bdw = (unsigned long long*)(ws + off); off += (size_t)E * 8;
  int*   gtable = (int*)  (ws + off); off += (((size_t)L * 4) + 15) & ~(size_t)15;
  int*   rowptr = (int*)  (ws + off); off += (((size_t)(N + 1) * 4) + 15) & ~(size_t)15;
  float* dinv   = (float*)(ws + off); off += (size_t)N * 4;
  int*   bsum   = (int*)  (ws + off); off += 1024;
  unsigned short* WT1 = (unsigned short*)(ws + off); off += (size_t)FH * FIN * 2;  // bf16 W1^T
  unsigned short* WT2 = (unsigned short*)(ws + off); off += (size_t)FO * FH * 2;   // bf16 W2^T

  // weight transpose + bf16 cvt (tiny, off critical path)
  prep_w_kernel<<<(FIN * FH + FH * FO + 255) / 256, 256, 0, stream>>>(W1, W2, WT1, WT2);
  // CSR build (LDS-atomic bucketed) + MFMA gemm1 fused
  a1hist_gemm1_kernel<<<NBA + NBG, 256, 0, stream>>>(dst, gtable, E, NBA, NB,
                                                     x, WT1, h1q, N, NBG);
  scan1i_kernel<<<nsb, 256, 0, stream>>>(gtable, bsum, L);
  scan2_kernel<<<1, 256, 0, stream>>>(bsum, nsb);
  scan3_kernel<<<(L + 255) / 256, 256, 0, stream>>>(gtable, bsum, L);
  a3_bucketize_kernel<<<NBA, 1024, 0, stream>>>(src, dst, ew, gtable, bdw, E, NBA);
  b12_kernel<<<NB, 1024, 0, stream>>>(bdw, gtable, rowptr, dinv, edges,
                                      E, NBA, NB, N);
  fixup_kernel<<<(E + 255) / 256, 256, 0, stream>>>(edges, dinv, E);
  // layers
  agg1_kernel<<<(N * 64 + 255) / 256, 256, 0, stream>>>(h1q, edges, rowptr,
                                                        dinv, b1, a1b, N);
  gemm2_kernel<<<(N + 63) / 64, 256, 0, stream>>>(a1b, WT2, h2h, N);
  agg2_kernel<<<(N * 64 + 255) / 256, 256, 0, stream>>>(h2h, edges, rowptr,
                                                        dinv, b2, out, N);
}